// Round 10
// baseline (769.893 us; speedup 1.0000x reference)
//
#include <hip/hip_runtime.h>
#include <hip/hip_bf16.h>
#include <math.h>

#define DIM 1024
#define D_STATE 16
#define D_CONV 4
#define D_INNER 2048
#define DT_RANK 64
#define N_EXP 8
#define TOP_K 2
#define HID 2048
#define BB 2
#define TT 2048
#define NTOK (BB*TT)          // 4096
#define NSLOT (NTOK*TOP_K)    // 8192
#define EPS 1e-5f
#define NCHUNK 64
#define CLEN (TT/NCHUNK)      // 32
#define XPJ_KS 8
#define XPJ_KLEN (D_INNER/XPJ_KS)   // 256

// ---------------- workspace layout (float units) ----------------
#define OFF_R0   ((size_t)0)
#define OFF_R1   ((size_t)4194304)
#define OFF_R2   ((size_t)8388608)
#define OFF_XZ   ((size_t)10485760)
#define OFF_H    OFF_XZ
#define OFF_WU   ((size_t)18874368)
#define OFF_XCS  ((size_t)27262976)
#define OFF_DTP  ((size_t)35651584)
#define OFF_X1   ((size_t)44040192)
#define OFF_PROJ ((size_t)48234496)
#define OFF_TW   ((size_t)48627712)
#define OFF_INT  ((size_t)48635904)
#define OFF_XPW  ((size_t)48668672)
// int offsets (ints)
#define IO_TI    0
#define IO_CNT   8192
#define IO_CUR   8200
#define IO_OFS   8208
#define IO_TOK   8216
#define IO_SLOT  16408

typedef __attribute__((ext_vector_type(4))) float f32x4;
typedef __attribute__((ext_vector_type(8))) __bf16 bf16x8;
typedef __attribute__((ext_vector_type(4))) __bf16 bf16x4;

__device__ __forceinline__ float siluf(float v){ return v / (1.f + expf(-v)); }

__device__ __forceinline__ f32x4 mfma16(bf16x8 a, bf16x8 b, f32x4 c){
    return __builtin_amdgcn_mfma_f32_16x16x32_bf16(a, b, c, 0, 0, 0);
}

__device__ __forceinline__ void gload16(const void* g, void* l){
    __builtin_amdgcn_global_load_lds(
        (const __attribute__((address_space(1))) unsigned int*)g,
        (__attribute__((address_space(3))) unsigned int*)l, 16, 0, 0);
}

__device__ __forceinline__ void cvt_store16(__bf16* dst, f32x4 a0, f32x4 a1, f32x4 a2, f32x4 a3){
    bf16x8 p0, p1;
    #pragma unroll
    for (int j = 0; j < 4; ++j){
        p0[j]   = (__bf16)a0[j];
        p0[j+4] = (__bf16)a1[j];
        p1[j]   = (__bf16)a2[j];
        p1[j+4] = (__bf16)a3[j];
    }
    *(bf16x8*)dst = p0;
    *(bf16x8*)(dst+8) = p1;
}

// ---------------- weight f32 -> bf16 convert ----------------
__global__ __launch_bounds__(256) void cvt_w_kernel(const float* __restrict__ src,
    __bf16* __restrict__ dst, int n4)
{
    int i = blockIdx.x*256 + threadIdx.x;
    int stride = gridDim.x*256;
    for (; i < n4; i += stride){
        f32x4 v = *(const f32x4*)(src + (size_t)i*4);
        bf16x4 o;
        o[0] = (__bf16)v[0]; o[1] = (__bf16)v[1];
        o[2] = (__bf16)v[2]; o[3] = (__bf16)v[3];
        *(bf16x4*)(dst + (size_t)i*4) = o;
    }
}

// x_proj (96x2048) -> padded bf16 (128x2048), rows 96..127 = 0
__global__ __launch_bounds__(256) void cvt_pad_xproj(const float* __restrict__ src,
    __bf16* __restrict__ dst)
{
    int i = blockIdx.x*256 + threadIdx.x;
    int base = i*4;
    int row = base >> 11;
    bf16x4 o;
    if (row < 96){
        f32x4 v = *(const f32x4*)(src + base);
        o[0] = (__bf16)v[0]; o[1] = (__bf16)v[1];
        o[2] = (__bf16)v[2]; o[3] = (__bf16)v[3];
    } else {
        o[0] = (__bf16)0.f; o[1] = (__bf16)0.f;
        o[2] = (__bf16)0.f; o[3] = (__bf16)0.f;
    }
    *(bf16x4*)(dst + base) = o;
}

// ---------------- LayerNorm (LN1): bf16 out ----------------
__global__ __launch_bounds__(256) void ln_kernel(const float* __restrict__ x,
    const float* __restrict__ s, const float* __restrict__ b,
    __bf16* __restrict__ obf)
{
    int t = blockIdx.x;
    const float* xp = x + (size_t)t * DIM;
    float v[4]; float sum = 0.f, sq = 0.f;
    #pragma unroll
    for (int j = 0; j < 4; ++j){
        v[j] = xp[threadIdx.x + 256*j];
        sum += v[j]; sq += v[j]*v[j];
    }
    #pragma unroll
    for (int off = 32; off; off >>= 1){
        sum += __shfl_xor(sum, off, 64);
        sq  += __shfl_xor(sq , off, 64);
    }
    __shared__ float red[4][2];
    int w = threadIdx.x >> 6, lane = threadIdx.x & 63;
    if (lane == 0){ red[w][0] = sum; red[w][1] = sq; }
    __syncthreads();
    sum = red[0][0]+red[1][0]+red[2][0]+red[3][0];
    sq  = red[0][1]+red[1][1]+red[2][1]+red[3][1];
    float mu = sum * (1.f/DIM);
    float var = sq * (1.f/DIM) - mu*mu;
    float r = rsqrtf(var + EPS);
    #pragma unroll
    for (int j = 0; j < 4; ++j){
        int d = threadIdx.x + 256*j;
        obf[(size_t)t*DIM + d] = (__bf16)((v[j]-mu)*r*s[d] + b[d]);
    }
}

// ---------------- LN2 fused with router ----------------
__global__ __launch_bounds__(256) void ln2_router_kernel(const float* __restrict__ x,
    const float* __restrict__ s, const float* __restrict__ b,
    const float* __restrict__ rw, __bf16* __restrict__ obf,
    float* __restrict__ tw, int* __restrict__ ti, int* __restrict__ counts)
{
    int t = blockIdx.x;
    const float* xp = x + (size_t)t * DIM;
    float v[4]; float sum = 0.f, sq = 0.f;
    #pragma unroll
    for (int j = 0; j < 4; ++j){
        v[j] = xp[threadIdx.x + 256*j];
        sum += v[j]; sq += v[j]*v[j];
    }
    #pragma unroll
    for (int off = 32; off; off >>= 1){
        sum += __shfl_xor(sum, off, 64);
        sq  += __shfl_xor(sq , off, 64);
    }
    __shared__ float red[4][2];
    __shared__ float red2[4][N_EXP];
    int w = threadIdx.x >> 6, lane = threadIdx.x & 63;
    if (lane == 0){ red[w][0] = sum; red[w][1] = sq; }
    __syncthreads();
    sum = red[0][0]+red[1][0]+red[2][0]+red[3][0];
    sq  = red[0][1]+red[1][1]+red[2][1]+red[3][1];
    float mu = sum * (1.f/DIM);
    float var = sq * (1.f/DIM) - mu*mu;
    float r = rsqrtf(var + EPS);
    float p[N_EXP] = {};
    #pragma unroll
    for (int j = 0; j < 4; ++j){
        int d = threadIdx.x + 256*j;
        float o = (v[j]-mu)*r*s[d] + b[d];
        obf[(size_t)t*DIM + d] = (__bf16)o;
        #pragma unroll
        for (int e = 0; e < N_EXP; ++e) p[e] += o * rw[e*DIM + d];
    }
    #pragma unroll
    for (int e = 0; e < N_EXP; ++e){
        #pragma unroll
        for (int off = 32; off; off >>= 1) p[e] += __shfl_xor(p[e], off, 64);
    }
    if (lane == 0){
        #pragma unroll
        for (int e = 0; e < N_EXP; ++e) red2[w][e] = p[e];
    }
    __syncthreads();
    if (threadIdx.x == 0){
        float q[N_EXP];
        #pragma unroll
        for (int e = 0; e < N_EXP; ++e)
            q[e] = red2[0][e]+red2[1][e]+red2[2][e]+red2[3][e];
        float mx = q[0];
        #pragma unroll
        for (int e = 1; e < N_EXP; ++e) mx = fmaxf(mx, q[e]);
        float ssum = 0.f;
        #pragma unroll
        for (int e = 0; e < N_EXP; ++e){ q[e] = expf(q[e]-mx); ssum += q[e]; }
        int i0 = 0;
        #pragma unroll
        for (int e = 1; e < N_EXP; ++e) if (q[e] > q[i0]) i0 = e;
        int i1 = (i0 == 0) ? 1 : 0;
        #pragma unroll
        for (int e = 0; e < N_EXP; ++e) if (e != i0 && q[e] > q[i1]) i1 = e;
        float w0 = q[i0]/ssum, w1 = q[i1]/ssum;
        float sw = w0 + w1; w0 /= sw; w1 /= sw;
        tw[t*2] = w0; tw[t*2+1] = w1;
        ti[t*2] = i0; ti[t*2+1] = i1;
        atomicAdd(&counts[i0], 1);
        atomicAdd(&counts[i1], 1);
    }
}

// ============ fast bf16 MFMA GEMM: 3-buffer 2-deep prefetch + XOR swizzle ============
template<int MODE, int EPI, int CBF, int SWZ>
__global__ __launch_bounds__(256,3) void mfma_gemm_fast(
    const __bf16* __restrict__ A, const __bf16* __restrict__ W,
    const void* __restrict__ RG, void* __restrict__ Cv,
    const int* __restrict__ tok_of_slot, const int* __restrict__ counts,
    const int* __restrict__ offs, int M, int N, int K, int lda)
{
    int bx = blockIdx.x, by = blockIdx.y;
    if (SWZ){
        int nwg = gridDim.x*gridDim.y;
        int id = by*gridDim.x + bx;
        int swz = (id & 7)*(nwg >> 3) + (id >> 3);
        bx = swz % gridDim.x; by = swz / gridDim.x;
    }
    int e    = (MODE == 0) ? 0 : blockIdx.z;
    int cnt  = (MODE == 0) ? M : counts[e];
    int base = (MODE == 0) ? 0 : offs[e];
    int m0 = by * 128;
    if (m0 >= cnt) return;
    int n0 = bx * 128;
    const __bf16* We = W + (size_t)e * N * K;

    __shared__ __bf16 As[3*128*32];
    __shared__ __bf16 Ws[3*128*32];

    int tid = threadIdx.x;
    int wave = tid >> 6, lane = tid & 63;
    int c0 = wave*2, c1 = wave*2 + 1;
    int lr0 = c0*16 + (lane >> 2);
    int lr1 = c1*16 + (lane >> 2);
    int koff = (((lane & 3) ^ ((lane >> 3) & 3)) * 8);   // swizzled source colblock

    int ar0, ar1;
    {
        int m0c = m0 + lr0, m1c = m0 + lr1;
        if (MODE != 0){
            if (m0c >= cnt) m0c = cnt - 1;
            if (m1c >= cnt) m1c = cnt - 1;
        }
        if (MODE == 1){ ar0 = tok_of_slot[base + m0c]; ar1 = tok_of_slot[base + m1c]; }
        else if (MODE == 2){ ar0 = base + m0c; ar1 = base + m1c; }
        else { ar0 = m0c; ar1 = m1c; }
    }
    const __bf16* aS0 = A + (size_t)ar0 * lda + koff;
    const __bf16* aS1 = A + (size_t)ar1 * lda + koff;
    const __bf16* wS0 = We + (size_t)(n0 + lr0) * K + koff;
    const __bf16* wS1 = We + (size_t)(n0 + lr1) * K + koff;
    __bf16* ldsA0 = As + c0*512;
    __bf16* ldsA1 = As + c1*512;
    __bf16* ldsW0 = Ws + c0*512;
    __bf16* ldsW1 = Ws + c1*512;

    int wm = (wave >> 1) * 64, wn = (wave & 1) * 64;
    int fr = lane & 15;
    const int scb = (((lane >> 4) ^ ((lane >> 1) & 3)) * 8);  // swizzled read colblock

    f32x4 acc[4][4];
    #pragma unroll
    for (int i = 0; i < 4; ++i)
        #pragma unroll
        for (int j = 0; j < 4; ++j)
            acc[i][j] = (f32x4){0.f, 0.f, 0.f, 0.f};

    int NK = K >> 5;
    gload16(aS0, ldsA0);        gload16(aS1, ldsA1);
    gload16(wS0, ldsW0);        gload16(wS1, ldsW1);
    if (NK > 1){
        gload16(aS0 + 32, ldsA0 + 4096); gload16(aS1 + 32, ldsA1 + 4096);
        gload16(wS0 + 32, ldsW0 + 4096); gload16(wS1 + 32, ldsW1 + 4096);
    }

    int cur = 0;
    for (int t = 0; t < NK; ++t){
        if (t + 2 < NK){
            int nb = cur + 2; if (nb >= 3) nb -= 3;
            int off = nb*4096;
            size_t ko = (size_t)(t+2)*32;
            gload16(aS0 + ko, ldsA0 + off);
            gload16(aS1 + ko, ldsA1 + off);
            gload16(wS0 + ko, ldsW0 + off);
            gload16(wS1 + ko, ldsW1 + off);
            asm volatile("s_waitcnt vmcnt(8)" ::: "memory");
        } else if (t + 1 < NK){
            asm volatile("s_waitcnt vmcnt(4)" ::: "memory");
        } else {
            asm volatile("s_waitcnt vmcnt(0)" ::: "memory");
        }
        __builtin_amdgcn_s_barrier();
        int bo = cur*4096;
        bf16x8 af[4], bf[4];
        #pragma unroll
        for (int i = 0; i < 4; ++i)
            af[i] = *(const bf16x8*)&As[bo + (wm + i*16 + fr)*32 + scb];
        #pragma unroll
        for (int j = 0; j < 4; ++j)
            bf[j] = *(const bf16x8*)&Ws[bo + (wn + j*16 + fr)*32 + scb];
        __builtin_amdgcn_s_setprio(1);
        #pragma unroll
        for (int i = 0; i < 4; ++i)
            #pragma unroll
            for (int j = 0; j < 4; ++j)
                acc[i][j] = mfma16(af[i], bf[j], acc[i][j]);
        __builtin_amdgcn_s_setprio(0);
        __builtin_amdgcn_s_barrier();
        cur = cur + 1; if (cur >= 3) cur -= 3;
    }

    int orow = (lane >> 4) * 4;
    int ocol = lane & 15;
    #pragma unroll
    for (int i = 0; i < 4; ++i){
        #pragma unroll
        for (int jj = 0; jj < 4; ++jj){
            #pragma unroll
            for (int j = 0; j < 4; ++j){
                int m = m0 + wm + i*16 + orow + j;
                int n = n0 + wn + jj*16 + ocol;
                if (m < cnt){
                    size_t row = (size_t)(base + m);
                    float v = acc[i][jj][j];
                    if (EPI == 1) v += ((const float*)RG)[row * (size_t)N + n];
                    if (CBF) ((__bf16*)Cv)[row * (size_t)N + n] = (__bf16)v;
                    else     ((float* )Cv)[row * (size_t)N + n] = v;
                }
            }
        }
    }
}

// ======== fused MoE gate+up GEMM: BM=128 x BN=256, 512 thr (2x4 waves) ========
// FLOP/staged-byte = 2*128*256/(128+512) = 102 (2x the 64x128 tile).
// LDS = 3buf x (A 8KB + G 16KB + U 16KB) = 120KB -> 1 block/CU, 8 waves (2/SIMD).
// 2-deep prefetch, counted vmcnt(10). Staging: 5 gload16/wave (A:1, G:2, U:2).
__global__ __launch_bounds__(512,2) void moe_gateup_fast(
    const __bf16* __restrict__ A, const __bf16* __restrict__ Wg,
    const __bf16* __restrict__ Wu, const int* __restrict__ tok_of_slot,
    const int* __restrict__ counts, const int* __restrict__ offs,
    __bf16* __restrict__ H)
{
    int e = blockIdx.z;
    int cnt = counts[e];
    int base = offs[e];
    int n0 = blockIdx.x * 256;
    const __bf16* Wge = Wg + (size_t)e * HID * DIM;
    const __bf16* Wue = Wu + (size_t)e * HID * DIM;

    __shared__ __bf16 As[3*128*32];    // buf stride 4096 elems
    __shared__ __bf16 Gs[3*256*32];    // buf stride 8192 elems
    __shared__ __bf16 Us[3*256*32];

    int tid = threadIdx.x;
    int wave = tid >> 6, lane = tid & 63;
    int lrow = lane >> 2;
    int koff = (((lane & 3) ^ ((lane >> 3) & 3)) * 8);   // swizzled source colblock

    // weight sources: wave w stages G/U chunks 2w, 2w+1 (rows n0+32w .. +31)
    const __bf16* gS0 = Wge + (size_t)(n0 + wave*32      + lrow) * DIM + koff;
    const __bf16* gS1 = Wge + (size_t)(n0 + wave*32 + 16 + lrow) * DIM + koff;
    const __bf16* uS0 = Wue + (size_t)(n0 + wave*32      + lrow) * DIM + koff;
    const __bf16* uS1 = Wue + (size_t)(n0 + wave*32 + 16 + lrow) * DIM + koff;
    __bf16* ldsA  = As + wave*512;              // A chunk w (rows 16w..16w+15)
    __bf16* ldsG0 = Gs + (wave*2    )*512;
    __bf16* ldsG1 = Gs + (wave*2 + 1)*512;
    __bf16* ldsU0 = Us + (wave*2    )*512;
    __bf16* ldsU1 = Us + (wave*2 + 1)*512;

    int wm = (wave >> 2) * 64;                  // 2 wave-rows over BM=128
    int wn = (wave & 3) * 64;                   // 4 wave-cols over BN=256
    int fr = lane & 15;
    const int scb = (((lane >> 4) ^ ((lane >> 1) & 3)) * 8);
    int orow = (lane >> 4) * 4;
    int ocol = lane & 15;
    const int NK = DIM >> 5;   // 32

    for (int mb = blockIdx.y; mb * 128 < cnt; mb += gridDim.y){
        int m0 = mb * 128;
        int mc = m0 + wave*16 + lrow;
        if (mc >= cnt) mc = cnt - 1;
        const __bf16* aS = A + (size_t)tok_of_slot[base + mc] * DIM + koff;

        f32x4 accg[4][4], accu[4][4];
        #pragma unroll
        for (int i = 0; i < 4; ++i)
            #pragma unroll
            for (int j = 0; j < 4; ++j){
                accg[i][j] = (f32x4){0.f, 0.f, 0.f, 0.f};
                accu[i][j] = (f32x4){0.f, 0.f, 0.f, 0.f};
            }

        // prologue: stage tiles 0 (buf0) and 1 (buf1)
        gload16(aS, ldsA);
        gload16(gS0, ldsG0); gload16(gS1, ldsG1);
        gload16(uS0, ldsU0); gload16(uS1, ldsU1);
        gload16(aS + 32, ldsA + 4096);
        gload16(gS0 + 32, ldsG0 + 8192); gload16(gS1 + 32, ldsG1 + 8192);
        gload16(uS0 + 32, ldsU0 + 8192); gload16(uS1 + 32, ldsU1 + 8192);

        int cur = 0;
        for (int t = 0; t < NK; ++t){
            if (t + 2 < NK){
                int nb = cur + 2; if (nb >= 3) nb -= 3;
                size_t ko = (size_t)(t+2)*32;
                gload16(aS + ko, ldsA + nb*4096);
                gload16(gS0 + ko, ldsG0 + nb*8192);
                gload16(gS1 + ko, ldsG1 + nb*8192);
                gload16(uS0 + ko, ldsU0 + nb*8192);
                gload16(uS1 + ko, ldsU1 + nb*8192);
                asm volatile("s_waitcnt vmcnt(10)" ::: "memory");
            } else if (t + 1 < NK){
                asm volatile("s_waitcnt vmcnt(5)" ::: "memory");
            } else {
                asm volatile("s_waitcnt vmcnt(0)" ::: "memory");
            }
            __builtin_amdgcn_s_barrier();
            int boA = cur*4096, boW = cur*8192;
            bf16x8 af[4], gf[4], uf[4];
            #pragma unroll
            for (int i = 0; i < 4; ++i)
                af[i] = *(const bf16x8*)&As[boA + (wm + i*16 + fr)*32 + scb];
            #pragma unroll
            for (int j = 0; j < 4; ++j){
                gf[j] = *(const bf16x8*)&Gs[boW + (wn + j*16 + fr)*32 + scb];
                uf[j] = *(const bf16x8*)&Us[boW + (wn + j*16 + fr)*32 + scb];
            }
            __builtin_amdgcn_s_setprio(1);
            #pragma unroll
            for (int i = 0; i < 4; ++i)
                #pragma unroll
                for (int j = 0; j < 4; ++j){
                    accg[i][j] = mfma16(af[i], gf[j], accg[i][j]);
                    accu[i][j] = mfma16(af[i], uf[j], accu[i][j]);
                }
            __builtin_amdgcn_s_setprio(0);
            __builtin_amdgcn_s_barrier();
            cur = cur + 1; if (cur >= 3) cur -= 3;
        }

        // epilogue: H[slot][n0 + wn + j*16 + ocol]
        #pragma unroll
        for (int i = 0; i < 4; ++i){
            #pragma unroll
            for (int j = 0; j < 4; ++j){
                #pragma unroll
                for (int j4 = 0; j4 < 4; ++j4){
                    int m = m0 + wm + i*16 + orow + j4;
                    if (m < cnt){
                        size_t row = (size_t)(base + m);
                        int n = n0 + wn + j*16 + ocol;
                        float g = accg[i][j][j4], u = accu[i][j][j4];
                        H[row * (size_t)HID + n] = (__bf16)(siluf(g) * u);
                    }
                }
            }
        }
    }
}

// ---------------- x_proj K-split GEMM (3-buffer 2-deep + swizzle) ----------------
__global__ __launch_bounds__(256,3) void xproj_ks_kernel(
    const __bf16* __restrict__ A, const __bf16* __restrict__ W,
    float* __restrict__ Cpart)
{
    int m0 = blockIdx.y * 128;
    int kbeg = blockIdx.z * XPJ_KLEN;

    __shared__ __bf16 As[3*128*32];
    __shared__ __bf16 Ws[3*128*32];

    int tid = threadIdx.x;
    int wave = tid >> 6, lane = tid & 63;
    int c0 = wave*2, c1 = wave*2 + 1;
    int lr0 = c0*16 + (lane >> 2);
    int lr1 = c1*16 + (lane >> 2);
    int koff = (((lane & 3) ^ ((lane >> 3) & 3)) * 8);

    const __bf16* aS0 = A + (size_t)(m0 + lr0) * D_INNER + kbeg + koff;
    const __bf16* aS1 = A + (size_t)(m0 + lr1) * D_INNER + kbeg + koff;
    const __bf16* wS0 = W + (size_t)lr0 * D_INNER + kbeg + koff;
    const __bf16* wS1 = W + (size_t)lr1 * D_INNER + kbeg + koff;
    __bf16* ldsA0 = As + c0*512;
    __bf16* ldsA1 = As + c1*512;
    __bf16* ldsW0 = Ws + c0*512;
    __bf16* ldsW1 = Ws + c1*512;

    int wm = (wave >> 1) * 64, wn = (wave & 1) * 64;
    int fr = lane & 15;
    const int scb = (((lane >> 4) ^ ((lane >> 1) & 3)) * 8);

    f32x4 acc[4][4];
    #pragma unroll
    for (int i = 0; i < 4; ++i)
        #pragma unroll
        for (int j = 0; j < 4; ++j)
            acc[i][j] = (f32x4){0.f, 0.f, 0.f, 0.f};

    gload16(aS0, ldsA0); gload16(aS1, ldsA1);
    gload16(wS0, ldsW0); gload16(wS1, ldsW1);
    gload16(aS0 + 32, ldsA0 + 4096); gload16(aS1 + 32, ldsA1 + 4096);
    gload16(wS0 + 32, ldsW0 + 4096); gload16(wS1 + 32, ldsW1 + 4096);

    const int NK = XPJ_KLEN >> 5;   // 8
    int cur = 0;
    for (int t = 0; t < NK; ++t){
        if (t + 2 < NK){
            int nb = cur + 2; if (nb >= 3) nb -= 3;
            int off = nb*4096;
            size_t ko = (size_t)(t+2)*32;
            gload16(aS0 + ko, ldsA0 + off);
            gload16(aS1 + ko, ldsA1 + off);
            gload16(wS0 + ko, ldsW0 + off);
            gload16(wS1 + ko, ldsW1 + off);
            asm volatile("s_waitcnt vmcnt(8)" ::: "memory");
        } else if (t + 1 < NK){
            asm volatile("s_waitcnt vmcnt(4)" ::: "memory");
        } else {
            asm volatile("s_waitcnt vmcnt(0)" ::: "memory");
        }
        __builtin_amdgcn_s_barrier();
        int bo = cur*4096;
        bf16x8 af[4], bf[4];
        #pragma unroll
        for (int i = 0; i < 4; ++i)
            af[i] = *(const bf16x8*)&As[bo + (wm + i*16 + fr)*32 + scb];
        #pragma unroll
        for (int j = 0; j < 4; ++j)
            bf[j] = *(const bf16x8*)&Ws[bo + (wn + j*16 + fr)*32 + scb];
        __builtin_amdgcn_s_setprio(1);
        #pragma unroll
        for (int i = 0; i < 4; ++i)
            #pragma unroll
            for (int j = 0; j < 4; ++j)
                acc[i][j] = mfma16(af[i], bf[j], acc[i][j]);
        __builtin_amdgcn_s_setprio(0);
        __builtin_amdgcn_s_barrier();
        cur = cur + 1; if (cur >= 3) cur -= 3;
    }

    float* Cz = Cpart + (size_t)blockIdx.z * NTOK * 128;
    int orow = (lane >> 4) * 4;
    int ocol = lane & 15;
    #pragma unroll
    for (int i = 0; i < 4; ++i){
        #pragma unroll
        for (int jj = 0; jj < 4; ++jj){
            #pragma unroll
            for (int j = 0; j < 4; ++j){
                int m = m0 + wm + i*16 + orow + j;
                int n = wn + jj*16 + ocol;
                Cz[(size_t)m * 128 + n] = acc[i][jj][j];
            }
        }
    }
}

__global__ __launch_bounds__(256) void xproj_reduce(const float* __restrict__ Cpart,
    float* __restrict__ proj)
{
    int idx = blockIdx.x*256 + threadIdx.x;
    int t = idx / 96, n = idx - t*96;
    float s = 0.f;
    #pragma unroll
    for (int z = 0; z < XPJ_KS; ++z)
        s += Cpart[(size_t)z * NTOK * 128 + (size_t)t * 128 + n];
    proj[idx] = s;
}

// ---------------- reg-staging MFMA GEMM (dt: softplus(A@W^T + bias)) ----------------
__global__ __launch_bounds__(256,2) void dt_gemm(
    const float* __restrict__ A, const float* __restrict__ W,
    const float* __restrict__ bias, float* __restrict__ C,
    int M, int N, int K, int lda)
{
    int m0 = blockIdx.y * 128;
    int n0 = blockIdx.x * 128;

    __shared__ __bf16 As[128*32];
    __shared__ __bf16 Ws[128*32];

    int tid = threadIdx.x;
    int srow = tid >> 1;
    int scol = (tid & 1) * 16;

    const float* af = A + (size_t)(m0 + srow) * lda + scol;
    const float* wptr = W + (size_t)(n0 + srow) * K + scol;

    f32x4 raf[4], rw[4];
    #pragma unroll
    for (int q = 0; q < 4; ++q){
        raf[q] = *(const f32x4*)(af + q*4);
        rw[q]  = *(const f32x4*)(wptr + q*4);
    }

    int wave = tid >> 6, lane = tid & 63;
    int wm = (wave >> 1) * 64, wn = (wave & 1) * 64;
    int fr = lane & 15, fk = (lane >> 4) * 8;

    f32x4 acc[4][4];
    #pragma unroll
    for (int i = 0; i < 4; ++i)
        #pragma unroll
        for (int j = 0; j < 4; ++j)
            acc[i][j] = (f32x4){0.f, 0.f, 0.f, 0.f};

    for (int k0 = 0; k0 < K; k0 += 32){
        cvt_store16(&As[srow*32 + scol], raf[0], raf[1], raf[2], raf[3]);
        cvt_store16(&Ws[srow*32 + scol], rw[0], rw[1], rw[2], rw[3]);
        __syncthreads();
        if (k0 + 32 < K){
            #pragma unroll
            for (int q = 0; q < 4; ++q){
                raf[q] = *(const f32x4*)(af + k0 + 32 + q*4);
                rw[q]  = *(const f32x4*)(wptr + k0 + 32 + q*4);
            }
        }
        bf16x8 afr[4], bfr[4];
        #pragma unroll
        for (int i = 0; i < 4; ++i)
            afr[i] = *(const bf16x8*)&As[(wm + i*16 + fr)*32 + fk];
        #pragma unroll
        for (int i = 0; i < 4; ++i)
            bfr[i] = *(const bf16x8*)&Ws[(wn + i*16 + fr)*32 + fk];
        #pragma unroll
        for (int i = 0; i < 4; ++i)
            #pragma unroll
            for (int j = 0; j < 4; ++j)
                acc[i][j] = mfma16(afr[i], bfr[j], acc[i][j]);
        __syncthreads();
    }

    int orow = (lane >> 4) * 4;
    int ocol = lane & 15;
    #pragma unroll
    for (int i = 0; i < 4; ++i){
        #pragma unroll
        for (int jj = 0; jj < 4; ++jj){
            #pragma unroll
            for (int j = 0; j < 4; ++j){
                int m = m0 + wm + i*16 + orow + j;
                int n = n0 + wn + jj*16 + ocol;
                if (m < M && n < N){
                    float v = acc[i][jj][j] + bias[n];
                    v = (v > 20.f) ? v : log1pf(expf(v));
                    C[(size_t)m * N + n] = v;
                }
            }
        }
    }
}

// ---------------- conv: f32 + bf16 outputs ----------------
__global__ __launch_bounds__(256) void conv_kernel(const float* __restrict__ xz,
    const float* __restrict__ cs, const float* __restrict__ cw,
    const float* __restrict__ cb, float* __restrict__ xcs,
    __bf16* __restrict__ xcs_bf)
{
    int idx = blockIdx.x*256 + threadIdx.x;
    int d = idx & (D_INNER-1);
    int bt = idx >> 11;
    int b = bt >> 11;
    int t = bt & (TT-1);
    float acc = cb[d];
    #pragma unroll
    for (int k = 0; k < 4; ++k){
        int tau = t + k - 3;
        float xv;
        if (tau >= 0) xv = xz[(size_t)(b*TT + tau)*(2*D_INNER) + d];
        else          xv = cs[((size_t)b*D_INNER + d)*3 + (tau + 3)];
        acc += cw[d*4 + k] * xv;
    }
    float v = siluf(acc);
    xcs[idx] = v;
    xcs_bf[idx] = (__bf16)v;
}

// ---------------- chunked SSM scan ----------------
__global__ __launch_bounds__(256) void scan_pass1(const float* __restrict__ dtp,
    const float* __restrict__ proj, const float* __restrict__ xcs,
    const float* __restrict__ A_log, float* __restrict__ hend,
    float* __restrict__ sumdt)
{
    int gid = blockIdx.x*256 + threadIdx.x;
    int bd = gid & (BB*D_INNER-1);
    int chunk = gid >> 12;
    int b = bd >> 11, d = bd & (D_INNER-1);
    float As[D_STATE], h[D_STATE];
    #pragma unroll
    for (int s = 0; s < D_STATE; ++s){
        As[s] = -__expf(A_log[d*D_STATE + s]);
        h[s] = 0.f;
    }
    float sdt = 0.f;
    int base = b*TT + chunk*CLEN;
    for (int t = 0; t < CLEN; ++t){
        size_t bt = (size_t)(base + t);
        float dt = dtp[bt*D_INNER + d];
        float x  = xcs[bt*D_INNER + d];
        f32x4 Bv[4];
        #pragma unroll
        for (int q = 0; q < 4; ++q) Bv[q] = *(const f32x4*)(proj + bt*96 + DT_RANK + q*4);
        float dtx = dt * x;
        sdt += dt;
        #pragma unroll
        for (int s = 0; s < D_STATE; ++s)
            h[s] = __expf(dt*As[s])*h[s] + Bv[s>>2][s&3]*dtx;
    }
    size_t hb = ((size_t)bd*NCHUNK + chunk)*D_STATE;
    #pragma unroll
    for (int q = 0; q < 4; ++q)
        *(f32x4*)(hend + hb + q*4) = (f32x4){h[q*4], h[q*4+1], h[q*4+2], h[q*4+3]};
    sumdt[bd*NCHUNK + chunk] = sdt;
}

__global__ __launch_bounds__(256) void scan_combine(const float* __restrict__ hend,
    const float* __restrict__ sumdt, const float* __restrict__ A_log,
    const float* __restrict__ ssm0, float* __restrict__ hstart)
{
    int gid = blockIdx.x*256 + threadIdx.x;
    int s = gid & 15;
    int bd = gid >> 4;
    int b = bd >> 11, d = bd & (D_INNER-1);
    float As = -__expf(A_log[d*D_STATE + s]);
    float h = ssm0[((size_t)b*D_INNER + d)*D_STATE + s];
    for (int c = 0; c < NCHUNK; ++c){
        size_t idx = ((size_t)bd*NCHUNK + c)*D_STATE + s;
        hstart[idx] = h;
        h = hend[idx] + __expf(As * sumdt[bd*NCHUNK + c]) * h;
    }
}

__global__ __launch_bounds__(256) void scan_pass3(const float* __restrict__ dtp,
    const float* __restrict__ proj, const float* __restrict__ xcs,
    const float* __restrict__ xz, const float* __restrict__ A_log,
    const float* __restrict__ Dp, const float* __restrict__ hstart,
    __bf16* __restrict__ ym)
{
    int gid = blockIdx.x*256 + threadIdx.x;
    int bd = gid & (BB*D_INNER-1);
    int chunk = gid >> 12;
    int b = bd >> 11, d = bd & (D_INNER-1);
    float As[D_STATE], h[D_STATE];
    #pragma unroll
    for (int s = 0; s < D_STATE; ++s)
        As[s] = -__expf(A_log[d*D_STATE + s]);
    size_t hb = ((size_t)bd*NCHUNK + chunk)*D_STATE;
    #pragma unroll
    for (int q = 0; q < 4; ++q){
        f32x4 hv = *(const f32x4*)(hstart + hb + q*4);
        h[q*4] = hv[0]; h[q*4+1] = hv[1]; h[q*4+2] = hv[2]; h[q*4+3] = hv[3];
    }
    float Dd = Dp[d];
    int base = b*TT + chunk*CLEN;
    for (int t = 0; t < CLEN; ++t){
        size_t bt = (size_t)(base + t);
        float dt = dtp[bt*D_INNER + d];
        float x  = xcs[bt*D_INNER + d];
        f32x4 Bv[4], Cv[4];
        #pragma unroll
        for (int q = 0; q < 4; ++q){
            Bv[q] = *(const f32x4*)(proj + bt*96 + DT_RANK + q*4);
            Cv[q] = *(const f32x4*)(proj + bt*96 + DT_RANK + D_STATE + q*4);
        }
        float dtx = dt * x;
        float p = 0.f;
        #pragma unroll
        for (int s = 0; s < D_STATE; ++s){
            h[s] = __expf(dt*As[s])*h[s] + Bv[s>>2][s&3]*dtx;
            p += h[s] * Cv[s>>2][s&3];
        }
        float y = p + Dd*x;
        float z = xz[bt*(2*D_INNER) + D_INNER + d];
        float sz = z / (1.f + __expf(-z));
        ym[bt*D_INNER + d] = (__bf16)(y * sz);
    }
}

// ---------------- slot assignment ----------------
__global__ void offs_kernel(const int* __restrict__ counts, int* __restrict__ offs)
{
    if (threadIdx.x == 0 && blockIdx.x == 0){
        int s = 0;
        for (int e = 0; e < N_EXP; ++e){ offs[e] = s; s += counts[e]; }
    }
}

__global__ __launch_bounds__(256) void assign_kernel(const int* __restrict__ ti,
    const int* __restrict__ offs, int* __restrict__ cursors,
    int* __restrict__ tok_of_slot, int* __restrict__ slot_of)
{
    int t = blockIdx.x*256 + threadIdx.x;
    if (t >= NTOK) return;
    #pragma unroll
    for (int k = 0; k < TOP_K; ++k){
        int e = ti[t*2 + k];
        int pos = atomicAdd(&cursors[e], 1);
        int slot = offs[e] + pos;
        tok_of_slot[slot] = t;
        slot_of[t*2 + k] = slot;
    }
}

// ---------------- final combine ----------------
__global__ __launch_bounds__(256) void final_kernel(const float* __restrict__ x1,
    const float* __restrict__ down_out, const float* __restrict__ tw,
    const int* __restrict__ slot_of, float* __restrict__ out)
{
    int idx4 = blockIdx.x*256 + threadIdx.x;
    int t = idx4 >> 8;
    int c = idx4 & 255;
    float w0 = tw[t*2], w1 = tw[t*2+1];
    size_t s0 = (size_t)slot_of[t*2] * DIM;
    size_t s1 = (size_t)slot_of[t*2+1] * DIM;
    float4 a = *(const float4*)(x1 + (size_t)t*DIM + c*4);
    float4 d0 = *(const float4*)(down_out + s0 + c*4);
    float4 d1 = *(const float4*)(down_out + s1 + c*4);
    float4 r;
    r.x = a.x + w0*d0.x + w1*d1.x;
    r.y = a.y + w0*d0.y + w1*d1.y;
    r.z = a.z + w0*d0.z + w1*d1.z;
    r.w = a.w + w0*d0.w + w1*d1.w;
    *(float4*)(out + (size_t)t*DIM + c*4) = r;
}

extern "C" void kernel_launch(void* const* d_in, const int* in_sizes, int n_in,
                              void* d_out, int out_size, void* d_ws, size_t ws_size,
                              hipStream_t stream)
{
    const float* x        = (const float*)d_in[0];
    const float* ssm0     = (const float*)d_in[1];
    const float* conv0    = (const float*)d_in[2];
    const float* ln1_s    = (const float*)d_in[3];
    const float* ln1_b    = (const float*)d_in[4];
    const float* ln2_s    = (const float*)d_in[5];
    const float* ln2_b    = (const float*)d_in[6];
    const float* in_proj  = (const float*)d_in[7];
    const float* conv_w   = (const float*)d_in[8];
    const float* conv_b   = (const float*)d_in[9];
    const float* x_proj   = (const float*)d_in[10];
    const float* dt_proj  = (const float*)d_in[11];
    const float* dt_b     = (const float*)d_in[12];
    const float* A_log    = (const float*)d_in[13];
    const float* Dp       = (const float*)d_in[14];
    const float* out_proj = (const float*)d_in[15];
    const float* router_w = (const float*)d_in[16];
    const float* w_gate   = (const float*)d_in[17];
    const float* w_up     = (const float*)d_in[18];
    const float* w_down   = (const float*)d_in[19];
    float* out = (float*)d_out;

    float* ws = (float*)d_ws;
    __bf16* xn_bf  = (__bf16*)(ws + OFF_R0);
    float*  hend   = ws + OFF_R0;
    __bf16* ym_bf  = (__bf16*)(ws + OFF_R0);
    float*  xpart  = ws + OFF_R1;
    float*  hst    = ws + OFF_R1;
    float*  sdt    = ws + OFF_R2;
    __bf16* opbf   = (__bf16*)(ws + OFF_R2);
    __bf16* xn2bf  = (__bf16*)(ws + OFF_R2);
    float*  xz     = ws + OFF_XZ;
    __bf16* H      = (__bf16*)(ws + OFF_H);
    __bf16* wubf   = (__bf16*)(ws + OFF_WU);
    float*  xcs    = ws + OFF_XCS;
    float*  dnout  = ws + OFF_XCS;
    float*  dtp    = ws + OFF_DTP;
    __bf16* ipbf   = (__bf16*)(ws + OFF_DTP);
    __bf16* wgbf   = (__bf16*)(ws + OFF_DTP);
    __bf16* wdbf   = (__bf16*)(ws + OFF_DTP);
    __bf16* xcs_bf = (__bf16*)(ws + OFF_X1);
    float*  x1     = ws + OFF_X1;
    float*  proj   = ws + OFF_PROJ;
    float*  tw     = ws + OFF_TW;
    __bf16* xpw    = (__bf16*)(ws + OFF_XPW);
    int*    ip     = (int*)(ws + OFF_INT);
    int* ti          = ip + IO_TI;
    int* counts      = ip + IO_CNT;
    int* cursors     = ip + IO_CUR;
    int* offs        = ip + IO_OFS;
    int* tok_of_slot = ip + IO_TOK;
    int* slot_of     = ip + IO_SLOT;

    hipMemsetAsync(counts, 0, 16*sizeof(int), stream);

    // 0a. in_proj -> bf16 (dtp region, dead until step 5)
    cvt_w_kernel<<<1024, 256, 0, stream>>>(in_proj, ipbf, (2*D_INNER*DIM)/4);
    // 1. xn_bf = LN1(x)
    ln_kernel<<<NTOK, 256, 0, stream>>>(x, ln1_s, ln1_b, xn_bf);
    // 2. xz = xn @ in_proj^T
    mfma_gemm_fast<0,0,0,1><<<dim3(32,32), 256, 0, stream>>>(xn_bf, ipbf, nullptr, xz,
        nullptr, nullptr, nullptr, NTOK, 2*D_INNER, DIM, DIM);
    // 3. conv + silu -> xcs f32 (scan) + xcs_bf (x_proj GEMM)
    conv_kernel<<<(NTOK*D_INNER)/256, 256, 0, stream>>>(xz, conv0, conv_w, conv_b, xcs, xcs_bf);
    // 4. proj = xcs @ x_proj^T  (K-split fast GEMM + reduce)
    cvt_pad_xproj<<<256, 256, 0, stream>>>(x_proj, xpw);
    xproj_ks_kernel<<<dim3(1,32,XPJ_KS), 256, 0, stream>>>(xcs_bf, xpw, xpart);
    xproj_reduce<<<(NTOK*96)/256, 256, 0, stream>>>(xpart, proj);
    // 5. dtp = softplus(proj[:,:64] @ dt_proj^T + dt_b)
    dt_gemm<<<dim3(16,32), 256, 0, stream>>>(proj, dt_proj, dt_b, dtp,
        NTOK, D_INNER, DT_RANK, 96);
    // 6. chunked scan
    scan_pass1<<<1024, 256, 0, stream>>>(dtp, proj, xcs, A_log, hend, sdt);
    scan_combine<<<256, 256, 0, stream>>>(hend, sdt, A_log, ssm0, hst);
    scan_pass3<<<1024, 256, 0, stream>>>(dtp, proj, xcs, xz, A_log, Dp, hst, ym_bf);
    // 6b. out_proj -> bf16 (R2; sdt dead after combine)
    cvt_w_kernel<<<512, 256, 0, stream>>>(out_proj, opbf, (DIM*D_INNER)/4);
    // 7. x1 = x + ym @ out_proj^T
    mfma_gemm_fast<0,1,0,1><<<dim3(8,32), 256, 0, stream>>>(ym_bf, opbf, x, x1,
        nullptr, nullptr, nullptr, NTOK, DIM, D_INNER, D_INNER);
    // 8. LN2 + router fused -> xn2bf, tw, ti, counts
    ln2_router_kernel<<<NTOK, 256, 0, stream>>>(x1, ln2_s, ln2_b, router_w,
        xn2bf, tw, ti, counts);
    // 9. slot assignment
    offs_kernel<<<1, 64, 0, stream>>>(counts, offs);
    assign_kernel<<<NTOK/256, 256, 0, stream>>>(ti, offs, cursors, tok_of_slot, slot_of);
    // 10. MoE: wg -> DTP region (dtp dead), wu -> XZ second half (xz dead); fused gate+up
    cvt_w_kernel<<<2048, 256, 0, stream>>>(w_gate, wgbf, (N_EXP*HID*DIM)/4);
    cvt_w_kernel<<<2048, 256, 0, stream>>>(w_up, wubf, (N_EXP*HID*DIM)/4);
    moe_gateup_fast<<<dim3(HID/256, 16, N_EXP), 512, 0, stream>>>(xn2bf, wgbf, wubf,
        tok_of_slot, counts, offs, H);
    // wd overwrites wg (dead after gateup)
    cvt_w_kernel<<<2048, 256, 0, stream>>>(w_down, wdbf, (N_EXP*DIM*HID)/4);
    mfma_gemm_fast<2,0,0,0><<<dim3(DIM/128, 64, N_EXP), 256, 0, stream>>>(H, wdbf, nullptr, dnout,
        tok_of_slot, counts, offs, NSLOT, DIM, HID, HID);
    // 11. out = x1 + weighted experts
    final_kernel<<<(NTOK*DIM/4)/256, 256, 0, stream>>>(x1, dnout, tw, slot_of, out);
}

// Round 13
// 734.428 us; speedup vs baseline: 1.0483x; 1.0483x over previous
//
#include <hip/hip_runtime.h>
#include <hip/hip_bf16.h>
#include <math.h>

#define DIM 1024
#define D_STATE 16
#define D_CONV 4
#define D_INNER 2048
#define DT_RANK 64
#define N_EXP 8
#define TOP_K 2
#define HID 2048
#define BB 2
#define TT 2048
#define NTOK (BB*TT)          // 4096
#define NSLOT (NTOK*TOP_K)    // 8192
#define EPS 1e-5f
#define NCHUNK 64
#define CLEN (TT/NCHUNK)      // 32
#define XPJ_KS 8
#define XPJ_KLEN (D_INNER/XPJ_KS)   // 256

// ---------------- workspace layout (float units) ----------------
#define OFF_R0   ((size_t)0)
#define OFF_R1   ((size_t)4194304)
#define OFF_R2   ((size_t)8388608)
#define OFF_XZ   ((size_t)10485760)
#define OFF_H    OFF_XZ
#define OFF_WU   ((size_t)18874368)
#define OFF_XCS  ((size_t)27262976)
#define OFF_DTP  ((size_t)35651584)
#define OFF_X1   ((size_t)44040192)
#define OFF_PROJ ((size_t)48234496)
#define OFF_TW   ((size_t)48627712)
#define OFF_INT  ((size_t)48635904)
#define OFF_XPW  ((size_t)48668672)
// int offsets (ints)
#define IO_TI    0
#define IO_CNT   8192
#define IO_CUR   8200
#define IO_OFS   8208
#define IO_TOK   8216
#define IO_SLOT  16408

typedef __attribute__((ext_vector_type(4))) float f32x4;
typedef __attribute__((ext_vector_type(8))) __bf16 bf16x8;
typedef __attribute__((ext_vector_type(4))) __bf16 bf16x4;

__device__ __forceinline__ float siluf(float v){ return v / (1.f + expf(-v)); }

__device__ __forceinline__ f32x4 mfma16(bf16x8 a, bf16x8 b, f32x4 c){
    return __builtin_amdgcn_mfma_f32_16x16x32_bf16(a, b, c, 0, 0, 0);
}

__device__ __forceinline__ void gload16(const void* g, void* l){
    __builtin_amdgcn_global_load_lds(
        (const __attribute__((address_space(1))) unsigned int*)g,
        (__attribute__((address_space(3))) unsigned int*)l, 16, 0, 0);
}

__device__ __forceinline__ void cvt_store16(__bf16* dst, f32x4 a0, f32x4 a1, f32x4 a2, f32x4 a3){
    bf16x8 p0, p1;
    #pragma unroll
    for (int j = 0; j < 4; ++j){
        p0[j]   = (__bf16)a0[j];
        p0[j+4] = (__bf16)a1[j];
        p1[j]   = (__bf16)a2[j];
        p1[j+4] = (__bf16)a3[j];
    }
    *(bf16x8*)dst = p0;
    *(bf16x8*)(dst+8) = p1;
}

// ---------------- weight f32 -> bf16 convert ----------------
__global__ __launch_bounds__(256) void cvt_w_kernel(const float* __restrict__ src,
    __bf16* __restrict__ dst, int n4)
{
    int i = blockIdx.x*256 + threadIdx.x;
    int stride = gridDim.x*256;
    for (; i < n4; i += stride){
        f32x4 v = *(const f32x4*)(src + (size_t)i*4);
        bf16x4 o;
        o[0] = (__bf16)v[0]; o[1] = (__bf16)v[1];
        o[2] = (__bf16)v[2]; o[3] = (__bf16)v[3];
        *(bf16x4*)(dst + (size_t)i*4) = o;
    }
}

// x_proj (96x2048) -> padded bf16 (128x2048), rows 96..127 = 0
__global__ __launch_bounds__(256) void cvt_pad_xproj(const float* __restrict__ src,
    __bf16* __restrict__ dst)
{
    int i = blockIdx.x*256 + threadIdx.x;
    int base = i*4;
    int row = base >> 11;
    bf16x4 o;
    if (row < 96){
        f32x4 v = *(const f32x4*)(src + base);
        o[0] = (__bf16)v[0]; o[1] = (__bf16)v[1];
        o[2] = (__bf16)v[2]; o[3] = (__bf16)v[3];
    } else {
        o[0] = (__bf16)0.f; o[1] = (__bf16)0.f;
        o[2] = (__bf16)0.f; o[3] = (__bf16)0.f;
    }
    *(bf16x4*)(dst + base) = o;
}

// ---------------- LayerNorm (LN1): bf16 out ----------------
__global__ __launch_bounds__(256) void ln_kernel(const float* __restrict__ x,
    const float* __restrict__ s, const float* __restrict__ b,
    __bf16* __restrict__ obf)
{
    int t = blockIdx.x;
    const float* xp = x + (size_t)t * DIM;
    float v[4]; float sum = 0.f, sq = 0.f;
    #pragma unroll
    for (int j = 0; j < 4; ++j){
        v[j] = xp[threadIdx.x + 256*j];
        sum += v[j]; sq += v[j]*v[j];
    }
    #pragma unroll
    for (int off = 32; off; off >>= 1){
        sum += __shfl_xor(sum, off, 64);
        sq  += __shfl_xor(sq , off, 64);
    }
    __shared__ float red[4][2];
    int w = threadIdx.x >> 6, lane = threadIdx.x & 63;
    if (lane == 0){ red[w][0] = sum; red[w][1] = sq; }
    __syncthreads();
    sum = red[0][0]+red[1][0]+red[2][0]+red[3][0];
    sq  = red[0][1]+red[1][1]+red[2][1]+red[3][1];
    float mu = sum * (1.f/DIM);
    float var = sq * (1.f/DIM) - mu*mu;
    float r = rsqrtf(var + EPS);
    #pragma unroll
    for (int j = 0; j < 4; ++j){
        int d = threadIdx.x + 256*j;
        obf[(size_t)t*DIM + d] = (__bf16)((v[j]-mu)*r*s[d] + b[d]);
    }
}

// ---------------- LN2 fused with router ----------------
__global__ __launch_bounds__(256) void ln2_router_kernel(const float* __restrict__ x,
    const float* __restrict__ s, const float* __restrict__ b,
    const float* __restrict__ rw, __bf16* __restrict__ obf,
    float* __restrict__ tw, int* __restrict__ ti, int* __restrict__ counts)
{
    int t = blockIdx.x;
    const float* xp = x + (size_t)t * DIM;
    float v[4]; float sum = 0.f, sq = 0.f;
    #pragma unroll
    for (int j = 0; j < 4; ++j){
        v[j] = xp[threadIdx.x + 256*j];
        sum += v[j]; sq += v[j]*v[j];
    }
    #pragma unroll
    for (int off = 32; off; off >>= 1){
        sum += __shfl_xor(sum, off, 64);
        sq  += __shfl_xor(sq , off, 64);
    }
    __shared__ float red[4][2];
    __shared__ float red2[4][N_EXP];
    int w = threadIdx.x >> 6, lane = threadIdx.x & 63;
    if (lane == 0){ red[w][0] = sum; red[w][1] = sq; }
    __syncthreads();
    sum = red[0][0]+red[1][0]+red[2][0]+red[3][0];
    sq  = red[0][1]+red[1][1]+red[2][1]+red[3][1];
    float mu = sum * (1.f/DIM);
    float var = sq * (1.f/DIM) - mu*mu;
    float r = rsqrtf(var + EPS);
    float p[N_EXP] = {};
    #pragma unroll
    for (int j = 0; j < 4; ++j){
        int d = threadIdx.x + 256*j;
        float o = (v[j]-mu)*r*s[d] + b[d];
        obf[(size_t)t*DIM + d] = (__bf16)o;
        #pragma unroll
        for (int e = 0; e < N_EXP; ++e) p[e] += o * rw[e*DIM + d];
    }
    #pragma unroll
    for (int e = 0; e < N_EXP; ++e){
        #pragma unroll
        for (int off = 32; off; off >>= 1) p[e] += __shfl_xor(p[e], off, 64);
    }
    if (lane == 0){
        #pragma unroll
        for (int e = 0; e < N_EXP; ++e) red2[w][e] = p[e];
    }
    __syncthreads();
    if (threadIdx.x == 0){
        float q[N_EXP];
        #pragma unroll
        for (int e = 0; e < N_EXP; ++e)
            q[e] = red2[0][e]+red2[1][e]+red2[2][e]+red2[3][e];
        float mx = q[0];
        #pragma unroll
        for (int e = 1; e < N_EXP; ++e) mx = fmaxf(mx, q[e]);
        float ssum = 0.f;
        #pragma unroll
        for (int e = 0; e < N_EXP; ++e){ q[e] = expf(q[e]-mx); ssum += q[e]; }
        int i0 = 0;
        #pragma unroll
        for (int e = 1; e < N_EXP; ++e) if (q[e] > q[i0]) i0 = e;
        int i1 = (i0 == 0) ? 1 : 0;
        #pragma unroll
        for (int e = 0; e < N_EXP; ++e) if (e != i0 && q[e] > q[i1]) i1 = e;
        float w0 = q[i0]/ssum, w1 = q[i1]/ssum;
        float sw = w0 + w1; w0 /= sw; w1 /= sw;
        tw[t*2] = w0; tw[t*2+1] = w1;
        ti[t*2] = i0; ti[t*2+1] = i1;
        atomicAdd(&counts[i0], 1);
        atomicAdd(&counts[i1], 1);
    }
}

// ============ fast bf16 MFMA GEMM: 3-buffer 2-deep prefetch + XOR swizzle ============
template<int MODE, int EPI, int CBF, int SWZ>
__global__ __launch_bounds__(256,3) void mfma_gemm_fast(
    const __bf16* __restrict__ A, const __bf16* __restrict__ W,
    const void* __restrict__ RG, void* __restrict__ Cv,
    const int* __restrict__ tok_of_slot, const int* __restrict__ counts,
    const int* __restrict__ offs, int M, int N, int K, int lda)
{
    int bx = blockIdx.x, by = blockIdx.y;
    if (SWZ){
        int nwg = gridDim.x*gridDim.y;
        int id = by*gridDim.x + bx;
        int swz = (id & 7)*(nwg >> 3) + (id >> 3);
        bx = swz % gridDim.x; by = swz / gridDim.x;
    }
    int e    = (MODE == 0) ? 0 : blockIdx.z;
    int cnt  = (MODE == 0) ? M : counts[e];
    int base = (MODE == 0) ? 0 : offs[e];
    int m0 = by * 128;
    if (m0 >= cnt) return;
    int n0 = bx * 128;
    const __bf16* We = W + (size_t)e * N * K;

    __shared__ __bf16 As[3*128*32];
    __shared__ __bf16 Ws[3*128*32];

    int tid = threadIdx.x;
    int wave = tid >> 6, lane = tid & 63;
    int c0 = wave*2, c1 = wave*2 + 1;
    int lr0 = c0*16 + (lane >> 2);
    int lr1 = c1*16 + (lane >> 2);
    int koff = (((lane & 3) ^ ((lane >> 3) & 3)) * 8);

    int ar0, ar1;
    {
        int m0c = m0 + lr0, m1c = m0 + lr1;
        if (MODE != 0){
            if (m0c >= cnt) m0c = cnt - 1;
            if (m1c >= cnt) m1c = cnt - 1;
        }
        if (MODE == 1){ ar0 = tok_of_slot[base + m0c]; ar1 = tok_of_slot[base + m1c]; }
        else if (MODE == 2){ ar0 = base + m0c; ar1 = base + m1c; }
        else { ar0 = m0c; ar1 = m1c; }
    }
    const __bf16* aS0 = A + (size_t)ar0 * lda + koff;
    const __bf16* aS1 = A + (size_t)ar1 * lda + koff;
    const __bf16* wS0 = We + (size_t)(n0 + lr0) * K + koff;
    const __bf16* wS1 = We + (size_t)(n0 + lr1) * K + koff;
    __bf16* ldsA0 = As + c0*512;
    __bf16* ldsA1 = As + c1*512;
    __bf16* ldsW0 = Ws + c0*512;
    __bf16* ldsW1 = Ws + c1*512;

    int wm = (wave >> 1) * 64, wn = (wave & 1) * 64;
    int fr = lane & 15;
    const int scb = (((lane >> 4) ^ ((lane >> 1) & 3)) * 8);

    f32x4 acc[4][4];
    #pragma unroll
    for (int i = 0; i < 4; ++i)
        #pragma unroll
        for (int j = 0; j < 4; ++j)
            acc[i][j] = (f32x4){0.f, 0.f, 0.f, 0.f};

    int NK = K >> 5;
    gload16(aS0, ldsA0);        gload16(aS1, ldsA1);
    gload16(wS0, ldsW0);        gload16(wS1, ldsW1);
    if (NK > 1){
        gload16(aS0 + 32, ldsA0 + 4096); gload16(aS1 + 32, ldsA1 + 4096);
        gload16(wS0 + 32, ldsW0 + 4096); gload16(wS1 + 32, ldsW1 + 4096);
    }

    int cur = 0;
    for (int t = 0; t < NK; ++t){
        if (t + 2 < NK){
            int nb = cur + 2; if (nb >= 3) nb -= 3;
            int off = nb*4096;
            size_t ko = (size_t)(t+2)*32;
            gload16(aS0 + ko, ldsA0 + off);
            gload16(aS1 + ko, ldsA1 + off);
            gload16(wS0 + ko, ldsW0 + off);
            gload16(wS1 + ko, ldsW1 + off);
            asm volatile("s_waitcnt vmcnt(8)" ::: "memory");
        } else if (t + 1 < NK){
            asm volatile("s_waitcnt vmcnt(4)" ::: "memory");
        } else {
            asm volatile("s_waitcnt vmcnt(0)" ::: "memory");
        }
        __builtin_amdgcn_s_barrier();
        int bo = cur*4096;
        bf16x8 af[4], bf[4];
        #pragma unroll
        for (int i = 0; i < 4; ++i)
            af[i] = *(const bf16x8*)&As[bo + (wm + i*16 + fr)*32 + scb];
        #pragma unroll
        for (int j = 0; j < 4; ++j)
            bf[j] = *(const bf16x8*)&Ws[bo + (wn + j*16 + fr)*32 + scb];
        __builtin_amdgcn_s_setprio(1);
        #pragma unroll
        for (int i = 0; i < 4; ++i)
            #pragma unroll
            for (int j = 0; j < 4; ++j)
                acc[i][j] = mfma16(af[i], bf[j], acc[i][j]);
        __builtin_amdgcn_s_setprio(0);
        __builtin_amdgcn_s_barrier();
        cur = cur + 1; if (cur >= 3) cur -= 3;
    }

    int orow = (lane >> 4) * 4;
    int ocol = lane & 15;
    #pragma unroll
    for (int i = 0; i < 4; ++i){
        #pragma unroll
        for (int jj = 0; jj < 4; ++jj){
            #pragma unroll
            for (int j = 0; j < 4; ++j){
                int m = m0 + wm + i*16 + orow + j;
                int n = n0 + wn + jj*16 + ocol;
                if (m < cnt){
                    size_t row = (size_t)(base + m);
                    float v = acc[i][jj][j];
                    if (EPI == 1) v += ((const float*)RG)[row * (size_t)N + n];
                    if (CBF) ((__bf16*)Cv)[row * (size_t)N + n] = (__bf16)v;
                    else     ((float* )Cv)[row * (size_t)N + n] = v;
                }
            }
        }
    }
}

// ======== fused MoE gate+up GEMM (R9 config: block 64x128, wave 64x32) ========
__global__ __launch_bounds__(256,3) void moe_gateup_fast(
    const __bf16* __restrict__ A, const __bf16* __restrict__ Wg,
    const __bf16* __restrict__ Wu, const int* __restrict__ tok_of_slot,
    const int* __restrict__ counts, const int* __restrict__ offs,
    __bf16* __restrict__ H)
{
    int e = blockIdx.z;
    int cnt = counts[e];
    int base = offs[e];
    int n0 = blockIdx.x * 128;
    const __bf16* Wge = Wg + (size_t)e * HID * DIM;
    const __bf16* Wue = Wu + (size_t)e * HID * DIM;

    __shared__ __bf16 As[2*64*32];
    __shared__ __bf16 Gs[2*128*32];
    __shared__ __bf16 Us[2*128*32];

    int tid = threadIdx.x;
    int wave = tid >> 6, lane = tid & 63;
    int lrow = lane >> 2;
    int koff = (((lane & 3) ^ ((lane >> 3) & 3)) * 8);

    const __bf16* gS0 = Wge + (size_t)(n0 + wave*32      + lrow) * DIM + koff;
    const __bf16* gS1 = Wge + (size_t)(n0 + wave*32 + 16 + lrow) * DIM + koff;
    const __bf16* uS0 = Wue + (size_t)(n0 + wave*32      + lrow) * DIM + koff;
    const __bf16* uS1 = Wue + (size_t)(n0 + wave*32 + 16 + lrow) * DIM + koff;
    __bf16* ldsA  = As + wave*512;
    __bf16* ldsG0 = Gs + (wave*2    )*512;
    __bf16* ldsG1 = Gs + (wave*2 + 1)*512;
    __bf16* ldsU0 = Us + (wave*2    )*512;
    __bf16* ldsU1 = Us + (wave*2 + 1)*512;

    int fr = lane & 15;
    const int scb = (((lane >> 4) ^ ((lane >> 1) & 3)) * 8);
    int orow = (lane >> 4) * 4;
    int ocol = lane & 15;
    const int NK = DIM >> 5;   // 32

    for (int mb = blockIdx.y; mb * 64 < cnt; mb += gridDim.y){
        int m0 = mb * 64;
        int mc = m0 + wave*16 + lrow;
        if (mc >= cnt) mc = cnt - 1;
        const __bf16* aS = A + (size_t)tok_of_slot[base + mc] * DIM + koff;

        f32x4 accg[4][2], accu[4][2];
        #pragma unroll
        for (int i = 0; i < 4; ++i)
            #pragma unroll
            for (int j = 0; j < 2; ++j){
                accg[i][j] = (f32x4){0.f, 0.f, 0.f, 0.f};
                accu[i][j] = (f32x4){0.f, 0.f, 0.f, 0.f};
            }

        gload16(aS, ldsA);
        gload16(gS0, ldsG0); gload16(gS1, ldsG1);
        gload16(uS0, ldsU0); gload16(uS1, ldsU1);

        int bo = 0;
        for (int t = 0; t < NK; ++t){
            if (t + 1 < NK){
                int nA = (bo ^ 1) * 2048, nW = (bo ^ 1) * 4096;
                size_t ko = (size_t)(t+1)*32;
                gload16(aS + ko, ldsA + nA);
                gload16(gS0 + ko, ldsG0 + nW); gload16(gS1 + ko, ldsG1 + nW);
                gload16(uS0 + ko, ldsU0 + nW); gload16(uS1 + ko, ldsU1 + nW);
                asm volatile("s_waitcnt vmcnt(5)" ::: "memory");
            } else {
                asm volatile("s_waitcnt vmcnt(0)" ::: "memory");
            }
            __builtin_amdgcn_s_barrier();
            int boA = bo*2048, boW = bo*4096;
            bf16x8 af[4], gf[2], uf[2];
            #pragma unroll
            for (int i = 0; i < 4; ++i)
                af[i] = *(const bf16x8*)&As[boA + (i*16 + fr)*32 + scb];
            #pragma unroll
            for (int j = 0; j < 2; ++j){
                gf[j] = *(const bf16x8*)&Gs[boW + (wave*32 + j*16 + fr)*32 + scb];
                uf[j] = *(const bf16x8*)&Us[boW + (wave*32 + j*16 + fr)*32 + scb];
            }
            __builtin_amdgcn_s_setprio(1);
            #pragma unroll
            for (int i = 0; i < 4; ++i)
                #pragma unroll
                for (int j = 0; j < 2; ++j){
                    accg[i][j] = mfma16(af[i], gf[j], accg[i][j]);
                    accu[i][j] = mfma16(af[i], uf[j], accu[i][j]);
                }
            __builtin_amdgcn_s_setprio(0);
            __builtin_amdgcn_s_barrier();
            bo ^= 1;
        }

        #pragma unroll
        for (int i = 0; i < 4; ++i){
            #pragma unroll
            for (int j = 0; j < 2; ++j){
                #pragma unroll
                for (int j4 = 0; j4 < 4; ++j4){
                    int m = m0 + i*16 + orow + j4;
                    if (m < cnt){
                        size_t row = (size_t)(base + m);
                        int n = n0 + wave*32 + j*16 + ocol;
                        float g = accg[i][j][j4], u = accu[i][j][j4];
                        H[row * (size_t)HID + n] = (__bf16)(siluf(g) * u);
                    }
                }
            }
        }
    }
}

// ---------------- x_proj K-split GEMM (3-buffer 2-deep + swizzle) ----------------
__global__ __launch_bounds__(256,3) void xproj_ks_kernel(
    const __bf16* __restrict__ A, const __bf16* __restrict__ W,
    float* __restrict__ Cpart)
{
    int m0 = blockIdx.y * 128;
    int kbeg = blockIdx.z * XPJ_KLEN;

    __shared__ __bf16 As[3*128*32];
    __shared__ __bf16 Ws[3*128*32];

    int tid = threadIdx.x;
    int wave = tid >> 6, lane = tid & 63;
    int c0 = wave*2, c1 = wave*2 + 1;
    int lr0 = c0*16 + (lane >> 2);
    int lr1 = c1*16 + (lane >> 2);
    int koff = (((lane & 3) ^ ((lane >> 3) & 3)) * 8);

    const __bf16* aS0 = A + (size_t)(m0 + lr0) * D_INNER + kbeg + koff;
    const __bf16* aS1 = A + (size_t)(m0 + lr1) * D_INNER + kbeg + koff;
    const __bf16* wS0 = W + (size_t)lr0 * D_INNER + kbeg + koff;
    const __bf16* wS1 = W + (size_t)lr1 * D_INNER + kbeg + koff;
    __bf16* ldsA0 = As + c0*512;
    __bf16* ldsA1 = As + c1*512;
    __bf16* ldsW0 = Ws + c0*512;
    __bf16* ldsW1 = Ws + c1*512;

    int wm = (wave >> 1) * 64, wn = (wave & 1) * 64;
    int fr = lane & 15;
    const int scb = (((lane >> 4) ^ ((lane >> 1) & 3)) * 8);

    f32x4 acc[4][4];
    #pragma unroll
    for (int i = 0; i < 4; ++i)
        #pragma unroll
        for (int j = 0; j < 4; ++j)
            acc[i][j] = (f32x4){0.f, 0.f, 0.f, 0.f};

    gload16(aS0, ldsA0); gload16(aS1, ldsA1);
    gload16(wS0, ldsW0); gload16(wS1, ldsW1);
    gload16(aS0 + 32, ldsA0 + 4096); gload16(aS1 + 32, ldsA1 + 4096);
    gload16(wS0 + 32, ldsW0 + 4096); gload16(wS1 + 32, ldsW1 + 4096);

    const int NK = XPJ_KLEN >> 5;   // 8
    int cur = 0;
    for (int t = 0; t < NK; ++t){
        if (t + 2 < NK){
            int nb = cur + 2; if (nb >= 3) nb -= 3;
            int off = nb*4096;
            size_t ko = (size_t)(t+2)*32;
            gload16(aS0 + ko, ldsA0 + off);
            gload16(aS1 + ko, ldsA1 + off);
            gload16(wS0 + ko, ldsW0 + off);
            gload16(wS1 + ko, ldsW1 + off);
            asm volatile("s_waitcnt vmcnt(8)" ::: "memory");
        } else if (t + 1 < NK){
            asm volatile("s_waitcnt vmcnt(4)" ::: "memory");
        } else {
            asm volatile("s_waitcnt vmcnt(0)" ::: "memory");
        }
        __builtin_amdgcn_s_barrier();
        int bo = cur*4096;
        bf16x8 af[4], bf[4];
        #pragma unroll
        for (int i = 0; i < 4; ++i)
            af[i] = *(const bf16x8*)&As[bo + (wm + i*16 + fr)*32 + scb];
        #pragma unroll
        for (int j = 0; j < 4; ++j)
            bf[j] = *(const bf16x8*)&Ws[bo + (wn + j*16 + fr)*32 + scb];
        __builtin_amdgcn_s_setprio(1);
        #pragma unroll
        for (int i = 0; i < 4; ++i)
            #pragma unroll
            for (int j = 0; j < 4; ++j)
                acc[i][j] = mfma16(af[i], bf[j], acc[i][j]);
        __builtin_amdgcn_s_setprio(0);
        __builtin_amdgcn_s_barrier();
        cur = cur + 1; if (cur >= 3) cur -= 3;
    }

    float* Cz = Cpart + (size_t)blockIdx.z * NTOK * 128;
    int orow = (lane >> 4) * 4;
    int ocol = lane & 15;
    #pragma unroll
    for (int i = 0; i < 4; ++i){
        #pragma unroll
        for (int jj = 0; jj < 4; ++jj){
            #pragma unroll
            for (int j = 0; j < 4; ++j){
                int m = m0 + wm + i*16 + orow + j;
                int n = wn + jj*16 + ocol;
                Cz[(size_t)m * 128 + n] = acc[i][jj][j];
            }
        }
    }
}

__global__ __launch_bounds__(256) void xproj_reduce(const float* __restrict__ Cpart,
    float* __restrict__ proj)
{
    int idx = blockIdx.x*256 + threadIdx.x;
    int t = idx / 96, n = idx - t*96;
    float s = 0.f;
    #pragma unroll
    for (int z = 0; z < XPJ_KS; ++z)
        s += Cpart[(size_t)z * NTOK * 128 + (size_t)t * 128 + n];
    proj[idx] = s;
}

// ---------------- reg-staging MFMA GEMM (dt: softplus(A@W^T + bias)) ----------------
__global__ __launch_bounds__(256,2) void dt_gemm(
    const float* __restrict__ A, const float* __restrict__ W,
    const float* __restrict__ bias, float* __restrict__ C,
    int M, int N, int K, int lda)
{
    int m0 = blockIdx.y * 128;
    int n0 = blockIdx.x * 128;

    __shared__ __bf16 As[128*32];
    __shared__ __bf16 Ws[128*32];

    int tid = threadIdx.x;
    int srow = tid >> 1;
    int scol = (tid & 1) * 16;

    const float* af = A + (size_t)(m0 + srow) * lda + scol;
    const float* wptr = W + (size_t)(n0 + srow) * K + scol;

    f32x4 raf[4], rw[4];
    #pragma unroll
    for (int q = 0; q < 4; ++q){
        raf[q] = *(const f32x4*)(af + q*4);
        rw[q]  = *(const f32x4*)(wptr + q*4);
    }

    int wave = tid >> 6, lane = tid & 63;
    int wm = (wave >> 1) * 64, wn = (wave & 1) * 64;
    int fr = lane & 15, fk = (lane >> 4) * 8;

    f32x4 acc[4][4];
    #pragma unroll
    for (int i = 0; i < 4; ++i)
        #pragma unroll
        for (int j = 0; j < 4; ++j)
            acc[i][j] = (f32x4){0.f, 0.f, 0.f, 0.f};

    for (int k0 = 0; k0 < K; k0 += 32){
        cvt_store16(&As[srow*32 + scol], raf[0], raf[1], raf[2], raf[3]);
        cvt_store16(&Ws[srow*32 + scol], rw[0], rw[1], rw[2], rw[3]);
        __syncthreads();
        if (k0 + 32 < K){
            #pragma unroll
            for (int q = 0; q < 4; ++q){
                raf[q] = *(const f32x4*)(af + k0 + 32 + q*4);
                rw[q]  = *(const f32x4*)(wptr + k0 + 32 + q*4);
            }
        }
        bf16x8 afr[4], bfr[4];
        #pragma unroll
        for (int i = 0; i < 4; ++i)
            afr[i] = *(const bf16x8*)&As[(wm + i*16 + fr)*32 + fk];
        #pragma unroll
        for (int i = 0; i < 4; ++i)
            bfr[i] = *(const bf16x8*)&Ws[(wn + i*16 + fr)*32 + fk];
        #pragma unroll
        for (int i = 0; i < 4; ++i)
            #pragma unroll
            for (int j = 0; j < 4; ++j)
                acc[i][j] = mfma16(afr[i], bfr[j], acc[i][j]);
        __syncthreads();
    }

    int orow = (lane >> 4) * 4;
    int ocol = lane & 15;
    #pragma unroll
    for (int i = 0; i < 4; ++i){
        #pragma unroll
        for (int jj = 0; jj < 4; ++jj){
            #pragma unroll
            for (int j = 0; j < 4; ++j){
                int m = m0 + wm + i*16 + orow + j;
                int n = n0 + wn + jj*16 + ocol;
                if (m < M && n < N){
                    float v = acc[i][jj][j] + bias[n];
                    v = (v > 20.f) ? v : log1pf(expf(v));
                    C[(size_t)m * N + n] = v;
                }
            }
        }
    }
}

// ---------------- conv: f32 + bf16 outputs ----------------
__global__ __launch_bounds__(256) void conv_kernel(const float* __restrict__ xz,
    const float* __restrict__ cs, const float* __restrict__ cw,
    const float* __restrict__ cb, float* __restrict__ xcs,
    __bf16* __restrict__ xcs_bf)
{
    int idx = blockIdx.x*256 + threadIdx.x;
    int d = idx & (D_INNER-1);
    int bt = idx >> 11;
    int b = bt >> 11;
    int t = bt & (TT-1);
    float acc = cb[d];
    #pragma unroll
    for (int k = 0; k < 4; ++k){
        int tau = t + k - 3;
        float xv;
        if (tau >= 0) xv = xz[(size_t)(b*TT + tau)*(2*D_INNER) + d];
        else          xv = cs[((size_t)b*D_INNER + d)*3 + (tau + 3)];
        acc += cw[d*4 + k] * xv;
    }
    float v = siluf(acc);
    xcs[idx] = v;
    xcs_bf[idx] = (__bf16)v;
}

// ---------------- chunked SSM scan ----------------
__global__ __launch_bounds__(256) void scan_pass1(const float* __restrict__ dtp,
    const float* __restrict__ proj, const float* __restrict__ xcs,
    const float* __restrict__ A_log, float* __restrict__ hend,
    float* __restrict__ sumdt)
{
    int gid = blockIdx.x*256 + threadIdx.x;
    int bd = gid & (BB*D_INNER-1);
    int chunk = gid >> 12;
    int b = bd >> 11, d = bd & (D_INNER-1);
    float As[D_STATE], h[D_STATE];
    #pragma unroll
    for (int s = 0; s < D_STATE; ++s){
        As[s] = -__expf(A_log[d*D_STATE + s]);
        h[s] = 0.f;
    }
    float sdt = 0.f;
    int base = b*TT + chunk*CLEN;
    for (int t = 0; t < CLEN; ++t){
        size_t bt = (size_t)(base + t);
        float dt = dtp[bt*D_INNER + d];
        float x  = xcs[bt*D_INNER + d];
        f32x4 Bv[4];
        #pragma unroll
        for (int q = 0; q < 4; ++q) Bv[q] = *(const f32x4*)(proj + bt*96 + DT_RANK + q*4);
        float dtx = dt * x;
        sdt += dt;
        #pragma unroll
        for (int s = 0; s < D_STATE; ++s)
            h[s] = __expf(dt*As[s])*h[s] + Bv[s>>2][s&3]*dtx;
    }
    size_t hb = ((size_t)bd*NCHUNK + chunk)*D_STATE;
    #pragma unroll
    for (int q = 0; q < 4; ++q)
        *(f32x4*)(hend + hb + q*4) = (f32x4){h[q*4], h[q*4+1], h[q*4+2], h[q*4+3]};
    sumdt[bd*NCHUNK + chunk] = sdt;
}

__global__ __launch_bounds__(256) void scan_combine(const float* __restrict__ hend,
    const float* __restrict__ sumdt, const float* __restrict__ A_log,
    const float* __restrict__ ssm0, float* __restrict__ hstart)
{
    int gid = blockIdx.x*256 + threadIdx.x;
    int s = gid & 15;
    int bd = gid >> 4;
    int b = bd >> 11, d = bd & (D_INNER-1);
    float As = -__expf(A_log[d*D_STATE + s]);
    float h = ssm0[((size_t)b*D_INNER + d)*D_STATE + s];
    for (int c = 0; c < NCHUNK; ++c){
        size_t idx = ((size_t)bd*NCHUNK + c)*D_STATE + s;
        hstart[idx] = h;
        h = hend[idx] + __expf(As * sumdt[bd*NCHUNK + c]) * h;
    }
}

__global__ __launch_bounds__(256) void scan_pass3(const float* __restrict__ dtp,
    const float* __restrict__ proj, const float* __restrict__ xcs,
    const float* __restrict__ xz, const float* __restrict__ A_log,
    const float* __restrict__ Dp, const float* __restrict__ hstart,
    __bf16* __restrict__ ym)
{
    int gid = blockIdx.x*256 + threadIdx.x;
    int bd = gid & (BB*D_INNER-1);
    int chunk = gid >> 12;
    int b = bd >> 11, d = bd & (D_INNER-1);
    float As[D_STATE], h[D_STATE];
    #pragma unroll
    for (int s = 0; s < D_STATE; ++s)
        As[s] = -__expf(A_log[d*D_STATE + s]);
    size_t hb = ((size_t)bd*NCHUNK + chunk)*D_STATE;
    #pragma unroll
    for (int q = 0; q < 4; ++q){
        f32x4 hv = *(const f32x4*)(hstart + hb + q*4);
        h[q*4] = hv[0]; h[q*4+1] = hv[1]; h[q*4+2] = hv[2]; h[q*4+3] = hv[3];
    }
    float Dd = Dp[d];
    int base = b*TT + chunk*CLEN;
    for (int t = 0; t < CLEN; ++t){
        size_t bt = (size_t)(base + t);
        float dt = dtp[bt*D_INNER + d];
        float x  = xcs[bt*D_INNER + d];
        f32x4 Bv[4], Cv[4];
        #pragma unroll
        for (int q = 0; q < 4; ++q){
            Bv[q] = *(const f32x4*)(proj + bt*96 + DT_RANK + q*4);
            Cv[q] = *(const f32x4*)(proj + bt*96 + DT_RANK + D_STATE + q*4);
        }
        float dtx = dt * x;
        float p = 0.f;
        #pragma unroll
        for (int s = 0; s < D_STATE; ++s){
            h[s] = __expf(dt*As[s])*h[s] + Bv[s>>2][s&3]*dtx;
            p += h[s] * Cv[s>>2][s&3];
        }
        float y = p + Dd*x;
        float z = xz[bt*(2*D_INNER) + D_INNER + d];
        float sz = z / (1.f + __expf(-z));
        ym[bt*D_INNER + d] = (__bf16)(y * sz);
    }
}

// ---------------- slot assignment ----------------
__global__ void offs_kernel(const int* __restrict__ counts, int* __restrict__ offs)
{
    if (threadIdx.x == 0 && blockIdx.x == 0){
        int s = 0;
        for (int e = 0; e < N_EXP; ++e){ offs[e] = s; s += counts[e]; }
    }
}

__global__ __launch_bounds__(256) void assign_kernel(const int* __restrict__ ti,
    const int* __restrict__ offs, int* __restrict__ cursors,
    int* __restrict__ tok_of_slot, int* __restrict__ slot_of)
{
    int t = blockIdx.x*256 + threadIdx.x;
    if (t >= NTOK) return;
    #pragma unroll
    for (int k = 0; k < TOP_K; ++k){
        int e = ti[t*2 + k];
        int pos = atomicAdd(&cursors[e], 1);
        int slot = offs[e] + pos;
        tok_of_slot[slot] = t;
        slot_of[t*2 + k] = slot;
    }
}

// ---------------- final combine (bf16 down_out) ----------------
__global__ __launch_bounds__(256) void final_kernel(const float* __restrict__ x1,
    const __bf16* __restrict__ down_out, const float* __restrict__ tw,
    const int* __restrict__ slot_of, float* __restrict__ out)
{
    int idx4 = blockIdx.x*256 + threadIdx.x;
    int t = idx4 >> 8;
    int c = idx4 & 255;
    float w0 = tw[t*2], w1 = tw[t*2+1];
    size_t s0 = (size_t)slot_of[t*2] * DIM;
    size_t s1 = (size_t)slot_of[t*2+1] * DIM;
    float4 a = *(const float4*)(x1 + (size_t)t*DIM + c*4);
    bf16x4 d0 = *(const bf16x4*)(down_out + s0 + c*4);
    bf16x4 d1 = *(const bf16x4*)(down_out + s1 + c*4);
    float4 r;
    r.x = a.x + w0*(float)d0[0] + w1*(float)d1[0];
    r.y = a.y + w0*(float)d0[1] + w1*(float)d1[1];
    r.z = a.z + w0*(float)d0[2] + w1*(float)d1[2];
    r.w = a.w + w0*(float)d0[3] + w1*(float)d1[3];
    *(float4*)(out + (size_t)t*DIM + c*4) = r;
}

extern "C" void kernel_launch(void* const* d_in, const int* in_sizes, int n_in,
                              void* d_out, int out_size, void* d_ws, size_t ws_size,
                              hipStream_t stream)
{
    const float* x        = (const float*)d_in[0];
    const float* ssm0     = (const float*)d_in[1];
    const float* conv0    = (const float*)d_in[2];
    const float* ln1_s    = (const float*)d_in[3];
    const float* ln1_b    = (const float*)d_in[4];
    const float* ln2_s    = (const float*)d_in[5];
    const float* ln2_b    = (const float*)d_in[6];
    const float* in_proj  = (const float*)d_in[7];
    const float* conv_w   = (const float*)d_in[8];
    const float* conv_b   = (const float*)d_in[9];
    const float* x_proj   = (const float*)d_in[10];
    const float* dt_proj  = (const float*)d_in[11];
    const float* dt_b     = (const float*)d_in[12];
    const float* A_log    = (const float*)d_in[13];
    const float* Dp       = (const float*)d_in[14];
    const float* out_proj = (const float*)d_in[15];
    const float* router_w = (const float*)d_in[16];
    const float* w_gate   = (const float*)d_in[17];
    const float* w_up     = (const float*)d_in[18];
    const float* w_down   = (const float*)d_in[19];
    float* out = (float*)d_out;

    float* ws = (float*)d_ws;
    __bf16* xn_bf  = (__bf16*)(ws + OFF_R0);
    float*  hend   = ws + OFF_R0;
    __bf16* ym_bf  = (__bf16*)(ws + OFF_R0);
    float*  xpart  = ws + OFF_R1;
    float*  hst    = ws + OFF_R1;
    float*  sdt    = ws + OFF_R2;
    __bf16* opbf   = (__bf16*)(ws + OFF_R2);
    __bf16* xn2bf  = (__bf16*)(ws + OFF_R2);
    float*  xz     = ws + OFF_XZ;
    __bf16* H      = (__bf16*)(ws + OFF_H);
    __bf16* wubf   = (__bf16*)(ws + OFF_WU);
    float*  xcs    = ws + OFF_XCS;
    __bf16* dnout  = (__bf16*)(ws + OFF_XCS);
    float*  dtp    = ws + OFF_DTP;
    __bf16* ipbf   = (__bf16*)(ws + OFF_DTP);
    __bf16* wgbf   = (__bf16*)(ws + OFF_DTP);
    __bf16* wdbf   = (__bf16*)(ws + OFF_DTP);
    __bf16* xcs_bf = (__bf16*)(ws + OFF_X1);
    float*  x1     = ws + OFF_X1;
    float*  proj   = ws + OFF_PROJ;
    float*  tw     = ws + OFF_TW;
    __bf16* xpw    = (__bf16*)(ws + OFF_XPW);
    int*    ip     = (int*)(ws + OFF_INT);
    int* ti          = ip + IO_TI;
    int* counts      = ip + IO_CNT;
    int* cursors     = ip + IO_CUR;
    int* offs        = ip + IO_OFS;
    int* tok_of_slot = ip + IO_TOK;
    int* slot_of     = ip + IO_SLOT;

    hipMemsetAsync(counts, 0, 16*sizeof(int), stream);

    // 0a. in_proj -> bf16 (dtp region, dead until step 5)
    cvt_w_kernel<<<1024, 256, 0, stream>>>(in_proj, ipbf, (2*D_INNER*DIM)/4);
    // 1. xn_bf = LN1(x)
    ln_kernel<<<NTOK, 256, 0, stream>>>(x, ln1_s, ln1_b, xn_bf);
    // 2. xz = xn @ in_proj^T  (f32 out — feeds conv and z-gate; pre-router precision)
    mfma_gemm_fast<0,0,0,1><<<dim3(32,32), 256, 0, stream>>>(xn_bf, ipbf, nullptr, xz,
        nullptr, nullptr, nullptr, NTOK, 2*D_INNER, DIM, DIM);
    // 3. conv + silu -> xcs f32 (scan) + xcs_bf (x_proj GEMM)
    conv_kernel<<<(NTOK*D_INNER)/256, 256, 0, stream>>>(xz, conv0, conv_w, conv_b, xcs, xcs_bf);
    // 4. proj = xcs @ x_proj^T  (K-split fast GEMM + reduce)
    cvt_pad_xproj<<<256, 256, 0, stream>>>(x_proj, xpw);
    xproj_ks_kernel<<<dim3(1,32,XPJ_KS), 256, 0, stream>>>(xcs_bf, xpw, xpart);
    xproj_reduce<<<(NTOK*96)/256, 256, 0, stream>>>(xpart, proj);
    // 5. dtp = softplus(proj[:,:64] @ dt_proj^T + dt_b)  (f32)
    dt_gemm<<<dim3(16,32), 256, 0, stream>>>(proj, dt_proj, dt_b, dtp,
        NTOK, D_INNER, DT_RANK, 96);
    // 6. chunked scan (f32 inputs)
    scan_pass1<<<1024, 256, 0, stream>>>(dtp, proj, xcs, A_log, hend, sdt);
    scan_combine<<<256, 256, 0, stream>>>(hend, sdt, A_log, ssm0, hst);
    scan_pass3<<<1024, 256, 0, stream>>>(dtp, proj, xcs, xz, A_log, Dp, hst, ym_bf);
    // 6b. out_proj -> bf16 (R2; sdt dead after combine)
    cvt_w_kernel<<<512, 256, 0, stream>>>(out_proj, opbf, (DIM*D_INNER)/4);
    // 7. x1 = x + ym @ out_proj^T
    mfma_gemm_fast<0,1,0,1><<<dim3(8,32), 256, 0, stream>>>(ym_bf, opbf, x, x1,
        nullptr, nullptr, nullptr, NTOK, DIM, D_INNER, D_INNER);
    // 8. LN2 + router fused -> xn2bf, tw, ti, counts
    ln2_router_kernel<<<NTOK, 256, 0, stream>>>(x1, ln2_s, ln2_b, router_w,
        xn2bf, tw, ti, counts);
    // 9. slot assignment
    offs_kernel<<<1, 64, 0, stream>>>(counts, offs);
    assign_kernel<<<NTOK/256, 256, 0, stream>>>(ti, offs, cursors, tok_of_slot, slot_of);
    // 10. MoE: fused gate+up, then down (bf16 out — post-router, linear)
    cvt_w_kernel<<<2048, 256, 0, stream>>>(w_gate, wgbf, (N_EXP*HID*DIM)/4);
    cvt_w_kernel<<<2048, 256, 0, stream>>>(w_up, wubf, (N_EXP*HID*DIM)/4);
    moe_gateup_fast<<<dim3(HID/128, 32, N_EXP), 256, 0, stream>>>(xn2bf, wgbf, wubf,
        tok_of_slot, counts, offs, H);
    cvt_w_kernel<<<2048, 256, 0, stream>>>(w_down, wdbf, (N_EXP*DIM*HID)/4);
    mfma_gemm_fast<2,0,1,0><<<dim3(DIM/128, 64, N_EXP), 256, 0, stream>>>(H, wdbf, nullptr, dnout,
        tok_of_slot, counts, offs, NSLOT, DIM, HID, HID);
    // 11. out = x1 + weighted experts
    final_kernel<<<(NTOK*DIM/4)/256, 256, 0, stream>>>(x1, dnout, tw, slot_of, out);
}

// Round 14
// 725.247 us; speedup vs baseline: 1.0616x; 1.0127x over previous
//
#include <hip/hip_runtime.h>
#include <hip/hip_bf16.h>
#include <math.h>

#define DIM 1024
#define D_STATE 16
#define D_CONV 4
#define D_INNER 2048
#define DT_RANK 64
#define N_EXP 8
#define TOP_K 2
#define HID 2048
#define BB 2
#define TT 2048
#define NTOK (BB*TT)          // 4096
#define NSLOT (NTOK*TOP_K)    // 8192
#define EPS 1e-5f
#define NCHUNK 64
#define CLEN (TT/NCHUNK)      // 32
#define XPJ_KS 8
#define XPJ_KLEN (D_INNER/XPJ_KS)   // 256

// ---------------- workspace layout (float units) ----------------
// R0: xn_bf16 (s1-2) -> hend (s6) -> ym_bf16 (s6c-7)
#define OFF_R0   ((size_t)0)
// R1: xproj partials (s4) -> hst (s6) -> dnout bf16 (s10c-11)
#define OFF_R1   ((size_t)4194304)
// R2: sdt (s6) -> out_proj_bf16 (s6b-7) -> xn2_bf16 (s8-10)
#define OFF_R2   ((size_t)8388608)
// XZ: xz f32 (s2-6c) -> H bf16 first half (s10) + wu bf16 second half (s10)
#define OFF_XZ   ((size_t)10485760)
#define OFF_H    OFF_XZ
#define OFF_WU   ((size_t)18874368)
// XCS region: wd bf16 (s10)
#define OFF_XCS  ((size_t)27262976)
// DTP: in_proj_bf16 (s2) -> dtp f32 (s5-6c) -> wg bf16 (s10)
#define OFF_DTP  ((size_t)35651584)
// X1: xcs_bf16 (s3-4) -> x1 f32 (s7-11)
#define OFF_X1   ((size_t)44040192)
#define OFF_PROJ ((size_t)48234496)
#define OFF_TW   ((size_t)48627712)
#define OFF_INT  ((size_t)48635904)
#define OFF_XPW  ((size_t)48668672)
// int offsets (ints)
#define IO_TI    0
#define IO_CNT   8192
#define IO_CUR   8200
#define IO_OFS   8208
#define IO_TOK   8216
#define IO_SLOT  16408

typedef __attribute__((ext_vector_type(4))) float f32x4;
typedef __attribute__((ext_vector_type(8))) __bf16 bf16x8;
typedef __attribute__((ext_vector_type(4))) __bf16 bf16x4;

__device__ __forceinline__ float siluf(float v){ return v / (1.f + expf(-v)); }

__device__ __forceinline__ f32x4 mfma16(bf16x8 a, bf16x8 b, f32x4 c){
    return __builtin_amdgcn_mfma_f32_16x16x32_bf16(a, b, c, 0, 0, 0);
}

__device__ __forceinline__ void gload16(const void* g, void* l){
    __builtin_amdgcn_global_load_lds(
        (const __attribute__((address_space(1))) unsigned int*)g,
        (__attribute__((address_space(3))) unsigned int*)l, 16, 0, 0);
}

__device__ __forceinline__ void cvt_store16(__bf16* dst, f32x4 a0, f32x4 a1, f32x4 a2, f32x4 a3){
    bf16x8 p0, p1;
    #pragma unroll
    for (int j = 0; j < 4; ++j){
        p0[j]   = (__bf16)a0[j];
        p0[j+4] = (__bf16)a1[j];
        p1[j]   = (__bf16)a2[j];
        p1[j+4] = (__bf16)a3[j];
    }
    *(bf16x8*)dst = p0;
    *(bf16x8*)(dst+8) = p1;
}

// ---------------- weight f32 -> bf16 convert (single) ----------------
__global__ __launch_bounds__(256) void cvt_w_kernel(const float* __restrict__ src,
    __bf16* __restrict__ dst, int n4)
{
    int i = blockIdx.x*256 + threadIdx.x;
    int stride = gridDim.x*256;
    for (; i < n4; i += stride){
        f32x4 v = *(const f32x4*)(src + (size_t)i*4);
        bf16x4 o;
        o[0] = (__bf16)v[0]; o[1] = (__bf16)v[1];
        o[2] = (__bf16)v[2]; o[3] = (__bf16)v[3];
        *(bf16x4*)(dst + (size_t)i*4) = o;
    }
}

// ---------------- triple weight cvt: wg, wu, wd in one dispatch ----------------
__global__ __launch_bounds__(256) void cvt_w3_kernel(
    const float* __restrict__ s0, __bf16* __restrict__ d0,
    const float* __restrict__ s1, __bf16* __restrict__ d1,
    const float* __restrict__ s2, __bf16* __restrict__ d2, int n4each)
{
    int stride = gridDim.x*256;
    for (int i = blockIdx.x*256 + threadIdx.x; i < n4each; i += stride){
        f32x4 v = *(const f32x4*)(s0 + (size_t)i*4);
        bf16x4 o;
        o[0]=(__bf16)v[0]; o[1]=(__bf16)v[1]; o[2]=(__bf16)v[2]; o[3]=(__bf16)v[3];
        *(bf16x4*)(d0 + (size_t)i*4) = o;
    }
    for (int i = blockIdx.x*256 + threadIdx.x; i < n4each; i += stride){
        f32x4 v = *(const f32x4*)(s1 + (size_t)i*4);
        bf16x4 o;
        o[0]=(__bf16)v[0]; o[1]=(__bf16)v[1]; o[2]=(__bf16)v[2]; o[3]=(__bf16)v[3];
        *(bf16x4*)(d1 + (size_t)i*4) = o;
    }
    for (int i = blockIdx.x*256 + threadIdx.x; i < n4each; i += stride){
        f32x4 v = *(const f32x4*)(s2 + (size_t)i*4);
        bf16x4 o;
        o[0]=(__bf16)v[0]; o[1]=(__bf16)v[1]; o[2]=(__bf16)v[2]; o[3]=(__bf16)v[3];
        *(bf16x4*)(d2 + (size_t)i*4) = o;
    }
}

// x_proj (96x2048) -> padded bf16 (128x2048), rows 96..127 = 0
__global__ __launch_bounds__(256) void cvt_pad_xproj(const float* __restrict__ src,
    __bf16* __restrict__ dst)
{
    int i = blockIdx.x*256 + threadIdx.x;
    int base = i*4;
    int row = base >> 11;
    bf16x4 o;
    if (row < 96){
        f32x4 v = *(const f32x4*)(src + base);
        o[0] = (__bf16)v[0]; o[1] = (__bf16)v[1];
        o[2] = (__bf16)v[2]; o[3] = (__bf16)v[3];
    } else {
        o[0] = (__bf16)0.f; o[1] = (__bf16)0.f;
        o[2] = (__bf16)0.f; o[3] = (__bf16)0.f;
    }
    *(bf16x4*)(dst + base) = o;
}

// ---------------- LayerNorm (LN1): bf16 out ----------------
__global__ __launch_bounds__(256) void ln_kernel(const float* __restrict__ x,
    const float* __restrict__ s, const float* __restrict__ b,
    __bf16* __restrict__ obf)
{
    int t = blockIdx.x;
    const float* xp = x + (size_t)t * DIM;
    float v[4]; float sum = 0.f, sq = 0.f;
    #pragma unroll
    for (int j = 0; j < 4; ++j){
        v[j] = xp[threadIdx.x + 256*j];
        sum += v[j]; sq += v[j]*v[j];
    }
    #pragma unroll
    for (int off = 32; off; off >>= 1){
        sum += __shfl_xor(sum, off, 64);
        sq  += __shfl_xor(sq , off, 64);
    }
    __shared__ float red[4][2];
    int w = threadIdx.x >> 6, lane = threadIdx.x & 63;
    if (lane == 0){ red[w][0] = sum; red[w][1] = sq; }
    __syncthreads();
    sum = red[0][0]+red[1][0]+red[2][0]+red[3][0];
    sq  = red[0][1]+red[1][1]+red[2][1]+red[3][1];
    float mu = sum * (1.f/DIM);
    float var = sq * (1.f/DIM) - mu*mu;
    float r = rsqrtf(var + EPS);
    #pragma unroll
    for (int j = 0; j < 4; ++j){
        int d = threadIdx.x + 256*j;
        obf[(size_t)t*DIM + d] = (__bf16)((v[j]-mu)*r*s[d] + b[d]);
    }
}

// ---------------- LN2 fused with router ----------------
__global__ __launch_bounds__(256) void ln2_router_kernel(const float* __restrict__ x,
    const float* __restrict__ s, const float* __restrict__ b,
    const float* __restrict__ rw, __bf16* __restrict__ obf,
    float* __restrict__ tw, int* __restrict__ ti, int* __restrict__ counts)
{
    int t = blockIdx.x;
    const float* xp = x + (size_t)t * DIM;
    float v[4]; float sum = 0.f, sq = 0.f;
    #pragma unroll
    for (int j = 0; j < 4; ++j){
        v[j] = xp[threadIdx.x + 256*j];
        sum += v[j]; sq += v[j]*v[j];
    }
    #pragma unroll
    for (int off = 32; off; off >>= 1){
        sum += __shfl_xor(sum, off, 64);
        sq  += __shfl_xor(sq , off, 64);
    }
    __shared__ float red[4][2];
    __shared__ float red2[4][N_EXP];
    int w = threadIdx.x >> 6, lane = threadIdx.x & 63;
    if (lane == 0){ red[w][0] = sum; red[w][1] = sq; }
    __syncthreads();
    sum = red[0][0]+red[1][0]+red[2][0]+red[3][0];
    sq  = red[0][1]+red[1][1]+red[2][1]+red[3][1];
    float mu = sum * (1.f/DIM);
    float var = sq * (1.f/DIM) - mu*mu;
    float r = rsqrtf(var + EPS);
    float p[N_EXP] = {};
    #pragma unroll
    for (int j = 0; j < 4; ++j){
        int d = threadIdx.x + 256*j;
        float o = (v[j]-mu)*r*s[d] + b[d];
        obf[(size_t)t*DIM + d] = (__bf16)o;
        #pragma unroll
        for (int e = 0; e < N_EXP; ++e) p[e] += o * rw[e*DIM + d];
    }
    #pragma unroll
    for (int e = 0; e < N_EXP; ++e){
        #pragma unroll
        for (int off = 32; off; off >>= 1) p[e] += __shfl_xor(p[e], off, 64);
    }
    if (lane == 0){
        #pragma unroll
        for (int e = 0; e < N_EXP; ++e) red2[w][e] = p[e];
    }
    __syncthreads();
    if (threadIdx.x == 0){
        float q[N_EXP];
        #pragma unroll
        for (int e = 0; e < N_EXP; ++e)
            q[e] = red2[0][e]+red2[1][e]+red2[2][e]+red2[3][e];
        float mx = q[0];
        #pragma unroll
        for (int e = 1; e < N_EXP; ++e) mx = fmaxf(mx, q[e]);
        float ssum = 0.f;
        #pragma unroll
        for (int e = 0; e < N_EXP; ++e){ q[e] = expf(q[e]-mx); ssum += q[e]; }
        int i0 = 0;
        #pragma unroll
        for (int e = 1; e < N_EXP; ++e) if (q[e] > q[i0]) i0 = e;
        int i1 = (i0 == 0) ? 1 : 0;
        #pragma unroll
        for (int e = 0; e < N_EXP; ++e) if (e != i0 && q[e] > q[i1]) i1 = e;
        float w0 = q[i0]/ssum, w1 = q[i1]/ssum;
        float sw = w0 + w1; w0 /= sw; w1 /= sw;
        tw[t*2] = w0; tw[t*2+1] = w1;
        ti[t*2] = i0; ti[t*2+1] = i1;
        atomicAdd(&counts[i0], 1);
        atomicAdd(&counts[i1], 1);
    }
}

// ============ fast bf16 MFMA GEMM: 3-buffer 2-deep prefetch + XOR swizzle ============
template<int MODE, int EPI, int CBF, int SWZ>
__global__ __launch_bounds__(256,3) void mfma_gemm_fast(
    const __bf16* __restrict__ A, const __bf16* __restrict__ W,
    const void* __restrict__ RG, void* __restrict__ Cv,
    const int* __restrict__ tok_of_slot, const int* __restrict__ counts,
    const int* __restrict__ offs, int M, int N, int K, int lda)
{
    int bx = blockIdx.x, by = blockIdx.y;
    if (SWZ){
        int nwg = gridDim.x*gridDim.y;
        int id = by*gridDim.x + bx;
        int swz = (id & 7)*(nwg >> 3) + (id >> 3);
        bx = swz % gridDim.x; by = swz / gridDim.x;
    }
    int e    = (MODE == 0) ? 0 : blockIdx.z;
    int cnt  = (MODE == 0) ? M : counts[e];
    int base = (MODE == 0) ? 0 : offs[e];
    int m0 = by * 128;
    if (m0 >= cnt) return;
    int n0 = bx * 128;
    const __bf16* We = W + (size_t)e * N * K;

    __shared__ __bf16 As[3*128*32];
    __shared__ __bf16 Ws[3*128*32];

    int tid = threadIdx.x;
    int wave = tid >> 6, lane = tid & 63;
    int c0 = wave*2, c1 = wave*2 + 1;
    int lr0 = c0*16 + (lane >> 2);
    int lr1 = c1*16 + (lane >> 2);
    int koff = (((lane & 3) ^ ((lane >> 3) & 3)) * 8);

    int ar0, ar1;
    {
        int m0c = m0 + lr0, m1c = m0 + lr1;
        if (MODE != 0){
            if (m0c >= cnt) m0c = cnt - 1;
            if (m1c >= cnt) m1c = cnt - 1;
        }
        if (MODE == 1){ ar0 = tok_of_slot[base + m0c]; ar1 = tok_of_slot[base + m1c]; }
        else if (MODE == 2){ ar0 = base + m0c; ar1 = base + m1c; }
        else { ar0 = m0c; ar1 = m1c; }
    }
    const __bf16* aS0 = A + (size_t)ar0 * lda + koff;
    const __bf16* aS1 = A + (size_t)ar1 * lda + koff;
    const __bf16* wS0 = We + (size_t)(n0 + lr0) * K + koff;
    const __bf16* wS1 = We + (size_t)(n0 + lr1) * K + koff;
    __bf16* ldsA0 = As + c0*512;
    __bf16* ldsA1 = As + c1*512;
    __bf16* ldsW0 = Ws + c0*512;
    __bf16* ldsW1 = Ws + c1*512;

    int wm = (wave >> 1) * 64, wn = (wave & 1) * 64;
    int fr = lane & 15;
    const int scb = (((lane >> 4) ^ ((lane >> 1) & 3)) * 8);

    f32x4 acc[4][4];
    #pragma unroll
    for (int i = 0; i < 4; ++i)
        #pragma unroll
        for (int j = 0; j < 4; ++j)
            acc[i][j] = (f32x4){0.f, 0.f, 0.f, 0.f};

    int NK = K >> 5;
    gload16(aS0, ldsA0);        gload16(aS1, ldsA1);
    gload16(wS0, ldsW0);        gload16(wS1, ldsW1);
    if (NK > 1){
        gload16(aS0 + 32, ldsA0 + 4096); gload16(aS1 + 32, ldsA1 + 4096);
        gload16(wS0 + 32, ldsW0 + 4096); gload16(wS1 + 32, ldsW1 + 4096);
    }

    int cur = 0;
    for (int t = 0; t < NK; ++t){
        if (t + 2 < NK){
            int nb = cur + 2; if (nb >= 3) nb -= 3;
            int off = nb*4096;
            size_t ko = (size_t)(t+2)*32;
            gload16(aS0 + ko, ldsA0 + off);
            gload16(aS1 + ko, ldsA1 + off);
            gload16(wS0 + ko, ldsW0 + off);
            gload16(wS1 + ko, ldsW1 + off);
            asm volatile("s_waitcnt vmcnt(8)" ::: "memory");
        } else if (t + 1 < NK){
            asm volatile("s_waitcnt vmcnt(4)" ::: "memory");
        } else {
            asm volatile("s_waitcnt vmcnt(0)" ::: "memory");
        }
        __builtin_amdgcn_s_barrier();
        int bo = cur*4096;
        bf16x8 af[4], bf[4];
        #pragma unroll
        for (int i = 0; i < 4; ++i)
            af[i] = *(const bf16x8*)&As[bo + (wm + i*16 + fr)*32 + scb];
        #pragma unroll
        for (int j = 0; j < 4; ++j)
            bf[j] = *(const bf16x8*)&Ws[bo + (wn + j*16 + fr)*32 + scb];
        __builtin_amdgcn_s_setprio(1);
        #pragma unroll
        for (int i = 0; i < 4; ++i)
            #pragma unroll
            for (int j = 0; j < 4; ++j)
                acc[i][j] = mfma16(af[i], bf[j], acc[i][j]);
        __builtin_amdgcn_s_setprio(0);
        __builtin_amdgcn_s_barrier();
        cur = cur + 1; if (cur >= 3) cur -= 3;
    }

    int orow = (lane >> 4) * 4;
    int ocol = lane & 15;
    #pragma unroll
    for (int i = 0; i < 4; ++i){
        #pragma unroll
        for (int jj = 0; jj < 4; ++jj){
            #pragma unroll
            for (int j = 0; j < 4; ++j){
                int m = m0 + wm + i*16 + orow + j;
                int n = n0 + wn + jj*16 + ocol;
                if (m < cnt){
                    size_t row = (size_t)(base + m);
                    float v = acc[i][jj][j];
                    if (EPI == 1) v += ((const float*)RG)[row * (size_t)N + n];
                    if (CBF) ((__bf16*)Cv)[row * (size_t)N + n] = (__bf16)v;
                    else     ((float* )Cv)[row * (size_t)N + n] = v;
                }
            }
        }
    }
}

// ======== fused MoE gate+up GEMM (R9 config: block 64x128, wave 64x32) ========
__global__ __launch_bounds__(256,3) void moe_gateup_fast(
    const __bf16* __restrict__ A, const __bf16* __restrict__ Wg,
    const __bf16* __restrict__ Wu, const int* __restrict__ tok_of_slot,
    const int* __restrict__ counts, const int* __restrict__ offs,
    __bf16* __restrict__ H)
{
    int e = blockIdx.z;
    int cnt = counts[e];
    int base = offs[e];
    int n0 = blockIdx.x * 128;
    const __bf16* Wge = Wg + (size_t)e * HID * DIM;
    const __bf16* Wue = Wu + (size_t)e * HID * DIM;

    __shared__ __bf16 As[2*64*32];
    __shared__ __bf16 Gs[2*128*32];
    __shared__ __bf16 Us[2*128*32];

    int tid = threadIdx.x;
    int wave = tid >> 6, lane = tid & 63;
    int lrow = lane >> 2;
    int koff = (((lane & 3) ^ ((lane >> 3) & 3)) * 8);

    const __bf16* gS0 = Wge + (size_t)(n0 + wave*32      + lrow) * DIM + koff;
    const __bf16* gS1 = Wge + (size_t)(n0 + wave*32 + 16 + lrow) * DIM + koff;
    const __bf16* uS0 = Wue + (size_t)(n0 + wave*32      + lrow) * DIM + koff;
    const __bf16* uS1 = Wue + (size_t)(n0 + wave*32 + 16 + lrow) * DIM + koff;
    __bf16* ldsA  = As + wave*512;
    __bf16* ldsG0 = Gs + (wave*2    )*512;
    __bf16* ldsG1 = Gs + (wave*2 + 1)*512;
    __bf16* ldsU0 = Us + (wave*2    )*512;
    __bf16* ldsU1 = Us + (wave*2 + 1)*512;

    int fr = lane & 15;
    const int scb = (((lane >> 4) ^ ((lane >> 1) & 3)) * 8);
    int orow = (lane >> 4) * 4;
    int ocol = lane & 15;
    const int NK = DIM >> 5;   // 32

    for (int mb = blockIdx.y; mb * 64 < cnt; mb += gridDim.y){
        int m0 = mb * 64;
        int mc = m0 + wave*16 + lrow;
        if (mc >= cnt) mc = cnt - 1;
        const __bf16* aS = A + (size_t)tok_of_slot[base + mc] * DIM + koff;

        f32x4 accg[4][2], accu[4][2];
        #pragma unroll
        for (int i = 0; i < 4; ++i)
            #pragma unroll
            for (int j = 0; j < 2; ++j){
                accg[i][j] = (f32x4){0.f, 0.f, 0.f, 0.f};
                accu[i][j] = (f32x4){0.f, 0.f, 0.f, 0.f};
            }

        gload16(aS, ldsA);
        gload16(gS0, ldsG0); gload16(gS1, ldsG1);
        gload16(uS0, ldsU0); gload16(uS1, ldsU1);

        int bo = 0;
        for (int t = 0; t < NK; ++t){
            if (t + 1 < NK){
                int nA = (bo ^ 1) * 2048, nW = (bo ^ 1) * 4096;
                size_t ko = (size_t)(t+1)*32;
                gload16(aS + ko, ldsA + nA);
                gload16(gS0 + ko, ldsG0 + nW); gload16(gS1 + ko, ldsG1 + nW);
                gload16(uS0 + ko, ldsU0 + nW); gload16(uS1 + ko, ldsU1 + nW);
                asm volatile("s_waitcnt vmcnt(5)" ::: "memory");
            } else {
                asm volatile("s_waitcnt vmcnt(0)" ::: "memory");
            }
            __builtin_amdgcn_s_barrier();
            int boA = bo*2048, boW = bo*4096;
            bf16x8 af[4], gf[2], uf[2];
            #pragma unroll
            for (int i = 0; i < 4; ++i)
                af[i] = *(const bf16x8*)&As[boA + (i*16 + fr)*32 + scb];
            #pragma unroll
            for (int j = 0; j < 2; ++j){
                gf[j] = *(const bf16x8*)&Gs[boW + (wave*32 + j*16 + fr)*32 + scb];
                uf[j] = *(const bf16x8*)&Us[boW + (wave*32 + j*16 + fr)*32 + scb];
            }
            __builtin_amdgcn_s_setprio(1);
            #pragma unroll
            for (int i = 0; i < 4; ++i)
                #pragma unroll
                for (int j = 0; j < 2; ++j){
                    accg[i][j] = mfma16(af[i], gf[j], accg[i][j]);
                    accu[i][j] = mfma16(af[i], uf[j], accu[i][j]);
                }
            __builtin_amdgcn_s_setprio(0);
            __builtin_amdgcn_s_barrier();
            bo ^= 1;
        }

        #pragma unroll
        for (int i = 0; i < 4; ++i){
            #pragma unroll
            for (int j = 0; j < 2; ++j){
                #pragma unroll
                for (int j4 = 0; j4 < 4; ++j4){
                    int m = m0 + i*16 + orow + j4;
                    if (m < cnt){
                        size_t row = (size_t)(base + m);
                        int n = n0 + wave*32 + j*16 + ocol;
                        float g = accg[i][j][j4], u = accu[i][j][j4];
                        H[row * (size_t)HID + n] = (__bf16)(siluf(g) * u);
                    }
                }
            }
        }
    }
}

// ---------------- x_proj K-split GEMM (3-buffer 2-deep + swizzle) ----------------
__global__ __launch_bounds__(256,3) void xproj_ks_kernel(
    const __bf16* __restrict__ A, const __bf16* __restrict__ W,
    float* __restrict__ Cpart)
{
    int m0 = blockIdx.y * 128;
    int kbeg = blockIdx.z * XPJ_KLEN;

    __shared__ __bf16 As[3*128*32];
    __shared__ __bf16 Ws[3*128*32];

    int tid = threadIdx.x;
    int wave = tid >> 6, lane = tid & 63;
    int c0 = wave*2, c1 = wave*2 + 1;
    int lr0 = c0*16 + (lane >> 2);
    int lr1 = c1*16 + (lane >> 2);
    int koff = (((lane & 3) ^ ((lane >> 3) & 3)) * 8);

    const __bf16* aS0 = A + (size_t)(m0 + lr0) * D_INNER + kbeg + koff;
    const __bf16* aS1 = A + (size_t)(m0 + lr1) * D_INNER + kbeg + koff;
    const __bf16* wS0 = W + (size_t)lr0 * D_INNER + kbeg + koff;
    const __bf16* wS1 = W + (size_t)lr1 * D_INNER + kbeg + koff;
    __bf16* ldsA0 = As + c0*512;
    __bf16* ldsA1 = As + c1*512;
    __bf16* ldsW0 = Ws + c0*512;
    __bf16* ldsW1 = Ws + c1*512;

    int wm = (wave >> 1) * 64, wn = (wave & 1) * 64;
    int fr = lane & 15;
    const int scb = (((lane >> 4) ^ ((lane >> 1) & 3)) * 8);

    f32x4 acc[4][4];
    #pragma unroll
    for (int i = 0; i < 4; ++i)
        #pragma unroll
        for (int j = 0; j < 4; ++j)
            acc[i][j] = (f32x4){0.f, 0.f, 0.f, 0.f};

    gload16(aS0, ldsA0); gload16(aS1, ldsA1);
    gload16(wS0, ldsW0); gload16(wS1, ldsW1);
    gload16(aS0 + 32, ldsA0 + 4096); gload16(aS1 + 32, ldsA1 + 4096);
    gload16(wS0 + 32, ldsW0 + 4096); gload16(wS1 + 32, ldsW1 + 4096);

    const int NK = XPJ_KLEN >> 5;   // 8
    int cur = 0;
    for (int t = 0; t < NK; ++t){
        if (t + 2 < NK){
            int nb = cur + 2; if (nb >= 3) nb -= 3;
            int off = nb*4096;
            size_t ko = (size_t)(t+2)*32;
            gload16(aS0 + ko, ldsA0 + off);
            gload16(aS1 + ko, ldsA1 + off);
            gload16(wS0 + ko, ldsW0 + off);
            gload16(wS1 + ko, ldsW1 + off);
            asm volatile("s_waitcnt vmcnt(8)" ::: "memory");
        } else if (t + 1 < NK){
            asm volatile("s_waitcnt vmcnt(4)" ::: "memory");
        } else {
            asm volatile("s_waitcnt vmcnt(0)" ::: "memory");
        }
        __builtin_amdgcn_s_barrier();
        int bo = cur*4096;
        bf16x8 af[4], bf[4];
        #pragma unroll
        for (int i = 0; i < 4; ++i)
            af[i] = *(const bf16x8*)&As[bo + (wm + i*16 + fr)*32 + scb];
        #pragma unroll
        for (int j = 0; j < 4; ++j)
            bf[j] = *(const bf16x8*)&Ws[bo + (wn + j*16 + fr)*32 + scb];
        __builtin_amdgcn_s_setprio(1);
        #pragma unroll
        for (int i = 0; i < 4; ++i)
            #pragma unroll
            for (int j = 0; j < 4; ++j)
                acc[i][j] = mfma16(af[i], bf[j], acc[i][j]);
        __builtin_amdgcn_s_setprio(0);
        __builtin_amdgcn_s_barrier();
        cur = cur + 1; if (cur >= 3) cur -= 3;
    }

    float* Cz = Cpart + (size_t)blockIdx.z * NTOK * 128;
    int orow = (lane >> 4) * 4;
    int ocol = lane & 15;
    #pragma unroll
    for (int i = 0; i < 4; ++i){
        #pragma unroll
        for (int jj = 0; jj < 4; ++jj){
            #pragma unroll
            for (int j = 0; j < 4; ++j){
                int m = m0 + wm + i*16 + orow + j;
                int n = wn + jj*16 + ocol;
                Cz[(size_t)m * 128 + n] = acc[i][jj][j];
            }
        }
    }
}

__global__ __launch_bounds__(256) void xproj_reduce(const float* __restrict__ Cpart,
    float* __restrict__ proj)
{
    int idx = blockIdx.x*256 + threadIdx.x;
    int t = idx / 96, n = idx - t*96;
    float s = 0.f;
    #pragma unroll
    for (int z = 0; z < XPJ_KS; ++z)
        s += Cpart[(size_t)z * NTOK * 128 + (size_t)t * 128 + n];
    proj[idx] = s;
}

// ---------------- reg-staging MFMA GEMM (dt: softplus(A@W^T + bias)) ----------------
__global__ __launch_bounds__(256,2) void dt_gemm(
    const float* __restrict__ A, const float* __restrict__ W,
    const float* __restrict__ bias, float* __restrict__ C,
    int M, int N, int K, int lda)
{
    int m0 = blockIdx.y * 128;
    int n0 = blockIdx.x * 128;

    __shared__ __bf16 As[128*32];
    __shared__ __bf16 Ws[128*32];

    int tid = threadIdx.x;
    int srow = tid >> 1;
    int scol = (tid & 1) * 16;

    const float* af = A + (size_t)(m0 + srow) * lda + scol;
    const float* wptr = W + (size_t)(n0 + srow) * K + scol;

    f32x4 raf[4], rw[4];
    #pragma unroll
    for (int q = 0; q < 4; ++q){
        raf[q] = *(const f32x4*)(af + q*4);
        rw[q]  = *(const f32x4*)(wptr + q*4);
    }

    int wave = tid >> 6, lane = tid & 63;
    int wm = (wave >> 1) * 64, wn = (wave & 1) * 64;
    int fr = lane & 15, fk = (lane >> 4) * 8;

    f32x4 acc[4][4];
    #pragma unroll
    for (int i = 0; i < 4; ++i)
        #pragma unroll
        for (int j = 0; j < 4; ++j)
            acc[i][j] = (f32x4){0.f, 0.f, 0.f, 0.f};

    for (int k0 = 0; k0 < K; k0 += 32){
        cvt_store16(&As[srow*32 + scol], raf[0], raf[1], raf[2], raf[3]);
        cvt_store16(&Ws[srow*32 + scol], rw[0], rw[1], rw[2], rw[3]);
        __syncthreads();
        if (k0 + 32 < K){
            #pragma unroll
            for (int q = 0; q < 4; ++q){
                raf[q] = *(const f32x4*)(af + k0 + 32 + q*4);
                rw[q]  = *(const f32x4*)(wptr + k0 + 32 + q*4);
            }
        }
        bf16x8 afr[4], bfr[4];
        #pragma unroll
        for (int i = 0; i < 4; ++i)
            afr[i] = *(const bf16x8*)&As[(wm + i*16 + fr)*32 + fk];
        #pragma unroll
        for (int i = 0; i < 4; ++i)
            bfr[i] = *(const bf16x8*)&Ws[(wn + i*16 + fr)*32 + fk];
        #pragma unroll
        for (int i = 0; i < 4; ++i)
            #pragma unroll
            for (int j = 0; j < 4; ++j)
                acc[i][j] = mfma16(afr[i], bfr[j], acc[i][j]);
        __syncthreads();
    }

    int orow = (lane >> 4) * 4;
    int ocol = lane & 15;
    #pragma unroll
    for (int i = 0; i < 4; ++i){
        #pragma unroll
        for (int jj = 0; jj < 4; ++jj){
            #pragma unroll
            for (int j = 0; j < 4; ++j){
                int m = m0 + wm + i*16 + orow + j;
                int n = n0 + wn + jj*16 + ocol;
                if (m < M && n < N){
                    float v = acc[i][jj][j] + bias[n];
                    v = (v > 20.f) ? v : log1pf(expf(v));
                    C[(size_t)m * N + n] = v;
                }
            }
        }
    }
}

// ---------------- conv: f32 xz in -> bf16 out only (xproj input) ----------------
__global__ __launch_bounds__(256) void conv_kernel(const float* __restrict__ xz,
    const float* __restrict__ cs, const float* __restrict__ cw,
    const float* __restrict__ cb, __bf16* __restrict__ xcs_bf)
{
    int idx = blockIdx.x*256 + threadIdx.x;
    int d = idx & (D_INNER-1);
    int bt = idx >> 11;
    int b = bt >> 11;
    int t = bt & (TT-1);
    float acc = cb[d];
    #pragma unroll
    for (int k = 0; k < 4; ++k){
        int tau = t + k - 3;
        float xv;
        if (tau >= 0) xv = xz[(size_t)(b*TT + tau)*(2*D_INNER) + d];
        else          xv = cs[((size_t)b*D_INNER + d)*3 + (tau + 3)];
        acc += cw[d*4 + k] * xv;
    }
    xcs_bf[idx] = (__bf16)siluf(acc);
}

// ---------------- chunked SSM scan with inline conv (f32-exact) ----------------
__global__ __launch_bounds__(256) void scan_pass1(const float* __restrict__ dtp,
    const float* __restrict__ proj, const float* __restrict__ xz,
    const float* __restrict__ cs, const float* __restrict__ cw,
    const float* __restrict__ cb, const float* __restrict__ A_log,
    float* __restrict__ hend, float* __restrict__ sumdt)
{
    int gid = blockIdx.x*256 + threadIdx.x;
    int bd = gid & (BB*D_INNER-1);
    int chunk = gid >> 12;
    int b = bd >> 11, d = bd & (D_INNER-1);
    float As[D_STATE], h[D_STATE];
    #pragma unroll
    for (int s = 0; s < D_STATE; ++s){
        As[s] = -__expf(A_log[d*D_STATE + s]);
        h[s] = 0.f;
    }
    float cw0 = cw[d*4], cw1 = cw[d*4+1], cw2 = cw[d*4+2], cw3 = cw[d*4+3];
    float cbd = cb[d];
    int t0 = chunk*CLEN;
    int base = b*TT + t0;
    float w0, w1, w2;
    if (chunk == 0){
        size_t cbase = ((size_t)b*D_INNER + d)*3;
        w0 = cs[cbase]; w1 = cs[cbase+1]; w2 = cs[cbase+2];
    } else {
        w0 = xz[(size_t)(base-3)*(2*D_INNER) + d];
        w1 = xz[(size_t)(base-2)*(2*D_INNER) + d];
        w2 = xz[(size_t)(base-1)*(2*D_INNER) + d];
    }
    float sdt = 0.f;
    for (int t = 0; t < CLEN; ++t){
        size_t bt = (size_t)(base + t);
        float dt = dtp[bt*D_INNER + d];
        float xv = xz[bt*(2*D_INNER) + d];
        float acc = cbd;
        acc += cw0*w0; acc += cw1*w1; acc += cw2*w2; acc += cw3*xv;
        float x = siluf(acc);
        w0 = w1; w1 = w2; w2 = xv;
        f32x4 Bv[4];
        #pragma unroll
        for (int q = 0; q < 4; ++q) Bv[q] = *(const f32x4*)(proj + bt*96 + DT_RANK + q*4);
        float dtx = dt * x;
        sdt += dt;
        #pragma unroll
        for (int s = 0; s < D_STATE; ++s)
            h[s] = __expf(dt*As[s])*h[s] + Bv[s>>2][s&3]*dtx;
    }
    size_t hb = ((size_t)bd*NCHUNK + chunk)*D_STATE;
    #pragma unroll
    for (int q = 0; q < 4; ++q)
        *(f32x4*)(hend + hb + q*4) = (f32x4){h[q*4], h[q*4+1], h[q*4+2], h[q*4+3]};
    sumdt[bd*NCHUNK + chunk] = sdt;
}

__global__ __launch_bounds__(256) void scan_combine(const float* __restrict__ hend,
    const float* __restrict__ sumdt, const float* __restrict__ A_log,
    const float* __restrict__ ssm0, float* __restrict__ hstart)
{
    int gid = blockIdx.x*256 + threadIdx.x;
    int s = gid & 15;
    int bd = gid >> 4;
    int b = bd >> 11, d = bd & (D_INNER-1);
    float As = -__expf(A_log[d*D_STATE + s]);
    float h = ssm0[((size_t)b*D_INNER + d)*D_STATE + s];
    for (int c = 0; c < NCHUNK; ++c){
        size_t idx = ((size_t)bd*NCHUNK + c)*D_STATE + s;
        hstart[idx] = h;
        h = hend[idx] + __expf(As * sumdt[bd*NCHUNK + c]) * h;
    }
}

__global__ __launch_bounds__(256) void scan_pass3(const float* __restrict__ dtp,
    const float* __restrict__ proj, const float* __restrict__ xz,
    const float* __restrict__ cs, const float* __restrict__ cw,
    const float* __restrict__ cb, const float* __restrict__ A_log,
    const float* __restrict__ Dp, const float* __restrict__ hstart,
    __bf16* __restrict__ ym)
{
    int gid = blockIdx.x*256 + threadIdx.x;
    int bd = gid & (BB*D_INNER-1);
    int chunk = gid >> 12;
    int b = bd >> 11, d = bd & (D_INNER-1);
    float As[D_STATE], h[D_STATE];
    #pragma unroll
    for (int s = 0; s < D_STATE; ++s)
        As[s] = -__expf(A_log[d*D_STATE + s]);
    size_t hb = ((size_t)bd*NCHUNK + chunk)*D_STATE;
    #pragma unroll
    for (int q = 0; q < 4; ++q){
        f32x4 hv = *(const f32x4*)(hstart + hb + q*4);
        h[q*4] = hv[0]; h[q*4+1] = hv[1]; h[q*4+2] = hv[2]; h[q*4+3] = hv[3];
    }
    float Dd = Dp[d];
    float cw0 = cw[d*4], cw1 = cw[d*4+1], cw2 = cw[d*4+2], cw3 = cw[d*4+3];
    float cbd = cb[d];
    int t0 = chunk*CLEN;
    int base = b*TT + t0;
    float w0, w1, w2;
    if (chunk == 0){
        size_t cbase = ((size_t)b*D_INNER + d)*3;
        w0 = cs[cbase]; w1 = cs[cbase+1]; w2 = cs[cbase+2];
    } else {
        w0 = xz[(size_t)(base-3)*(2*D_INNER) + d];
        w1 = xz[(size_t)(base-2)*(2*D_INNER) + d];
        w2 = xz[(size_t)(base-1)*(2*D_INNER) + d];
    }
    for (int t = 0; t < CLEN; ++t){
        size_t bt = (size_t)(base + t);
        float dt = dtp[bt*D_INNER + d];
        float xv = xz[bt*(2*D_INNER) + d];
        float acc = cbd;
        acc += cw0*w0; acc += cw1*w1; acc += cw2*w2; acc += cw3*xv;
        float x = siluf(acc);
        w0 = w1; w1 = w2; w2 = xv;
        f32x4 Bv[4], Cv[4];
        #pragma unroll
        for (int q = 0; q < 4; ++q){
            Bv[q] = *(const f32x4*)(proj + bt*96 + DT_RANK + q*4);
            Cv[q] = *(const f32x4*)(proj + bt*96 + DT_RANK + D_STATE + q*4);
        }
        float dtx = dt * x;
        float p = 0.f;
        #pragma unroll
        for (int s = 0; s < D_STATE; ++s){
            h[s] = __expf(dt*As[s])*h[s] + Bv[s>>2][s&3]*dtx;
            p += h[s] * Cv[s>>2][s&3];
        }
        float y = p + Dd*x;
        float z = xz[bt*(2*D_INNER) + D_INNER + d];
        float sz = z / (1.f + __expf(-z));
        ym[bt*D_INNER + d] = (__bf16)(y * sz);
    }
}

// ---------------- slot assignment ----------------
__global__ void offs_kernel(const int* __restrict__ counts, int* __restrict__ offs)
{
    if (threadIdx.x == 0 && blockIdx.x == 0){
        int s = 0;
        for (int e = 0; e < N_EXP; ++e){ offs[e] = s; s += counts[e]; }
    }
}

__global__ __launch_bounds__(256) void assign_kernel(const int* __restrict__ ti,
    const int* __restrict__ offs, int* __restrict__ cursors,
    int* __restrict__ tok_of_slot, int* __restrict__ slot_of)
{
    int t = blockIdx.x*256 + threadIdx.x;
    if (t >= NTOK) return;
    #pragma unroll
    for (int k = 0; k < TOP_K; ++k){
        int e = ti[t*2 + k];
        int pos = atomicAdd(&cursors[e], 1);
        int slot = offs[e] + pos;
        tok_of_slot[slot] = t;
        slot_of[t*2 + k] = slot;
    }
}

// ---------------- final combine (bf16 down_out) ----------------
__global__ __launch_bounds__(256) void final_kernel(const float* __restrict__ x1,
    const __bf16* __restrict__ down_out, const float* __restrict__ tw,
    const int* __restrict__ slot_of, float* __restrict__ out)
{
    int idx4 = blockIdx.x*256 + threadIdx.x;
    int t = idx4 >> 8;
    int c = idx4 & 255;
    float w0 = tw[t*2], w1 = tw[t*2+1];
    size_t s0 = (size_t)slot_of[t*2] * DIM;
    size_t s1 = (size_t)slot_of[t*2+1] * DIM;
    float4 a = *(const float4*)(x1 + (size_t)t*DIM + c*4);
    bf16x4 d0 = *(const bf16x4*)(down_out + s0 + c*4);
    bf16x4 d1 = *(const bf16x4*)(down_out + s1 + c*4);
    float4 r;
    r.x = a.x + w0*(float)d0[0] + w1*(float)d1[0];
    r.y = a.y + w0*(float)d0[1] + w1*(float)d1[1];
    r.z = a.z + w0*(float)d0[2] + w1*(float)d1[2];
    r.w = a.w + w0*(float)d0[3] + w1*(float)d1[3];
    *(float4*)(out + (size_t)t*DIM + c*4) = r;
}

extern "C" void kernel_launch(void* const* d_in, const int* in_sizes, int n_in,
                              void* d_out, int out_size, void* d_ws, size_t ws_size,
                              hipStream_t stream)
{
    const float* x        = (const float*)d_in[0];
    const float* ssm0     = (const float*)d_in[1];
    const float* conv0    = (const float*)d_in[2];
    const float* ln1_s    = (const float*)d_in[3];
    const float* ln1_b    = (const float*)d_in[4];
    const float* ln2_s    = (const float*)d_in[5];
    const float* ln2_b    = (const float*)d_in[6];
    const float* in_proj  = (const float*)d_in[7];
    const float* conv_w   = (const float*)d_in[8];
    const float* conv_b   = (const float*)d_in[9];
    const float* x_proj   = (const float*)d_in[10];
    const float* dt_proj  = (const float*)d_in[11];
    const float* dt_b     = (const float*)d_in[12];
    const float* A_log    = (const float*)d_in[13];
    const float* Dp       = (const float*)d_in[14];
    const float* out_proj = (const float*)d_in[15];
    const float* router_w = (const float*)d_in[16];
    const float* w_gate   = (const float*)d_in[17];
    const float* w_up     = (const float*)d_in[18];
    const float* w_down   = (const float*)d_in[19];
    float* out = (float*)d_out;

    float* ws = (float*)d_ws;
    __bf16* xn_bf  = (__bf16*)(ws + OFF_R0);
    float*  hend   = ws + OFF_R0;
    __bf16* ym_bf  = (__bf16*)(ws + OFF_R0);
    float*  xpart  = ws + OFF_R1;
    float*  hst    = ws + OFF_R1;
    __bf16* dnout  = (__bf16*)(ws + OFF_R1);
    float*  sdt    = ws + OFF_R2;
    __bf16* opbf   = (__bf16*)(ws + OFF_R2);
    __bf16* xn2bf  = (__bf16*)(ws + OFF_R2);
    float*  xz     = ws + OFF_XZ;
    __bf16* H      = (__bf16*)(ws + OFF_H);
    __bf16* wubf   = (__bf16*)(ws + OFF_WU);
    __bf16* wdbf   = (__bf16*)(ws + OFF_XCS);
    float*  dtp    = ws + OFF_DTP;
    __bf16* ipbf   = (__bf16*)(ws + OFF_DTP);
    __bf16* wgbf   = (__bf16*)(ws + OFF_DTP);
    __bf16* xcs_bf = (__bf16*)(ws + OFF_X1);
    float*  x1     = ws + OFF_X1;
    float*  proj   = ws + OFF_PROJ;
    float*  tw     = ws + OFF_TW;
    __bf16* xpw    = (__bf16*)(ws + OFF_XPW);
    int*    ip     = (int*)(ws + OFF_INT);
    int* ti          = ip + IO_TI;
    int* counts      = ip + IO_CNT;
    int* cursors     = ip + IO_CUR;
    int* offs        = ip + IO_OFS;
    int* tok_of_slot = ip + IO_TOK;
    int* slot_of     = ip + IO_SLOT;

    hipMemsetAsync(counts, 0, 16*sizeof(int), stream);

    // 0a. in_proj -> bf16 (dtp region, dead until step 5)
    cvt_w_kernel<<<1024, 256, 0, stream>>>(in_proj, ipbf, (2*D_INNER*DIM)/4);
    // 1. xn_bf = LN1(x)
    ln_kernel<<<NTOK, 256, 0, stream>>>(x, ln1_s, ln1_b, xn_bf);
    // 2. xz = xn @ in_proj^T  (f32 out — pre-router precision)
    mfma_gemm_fast<0,0,0,1><<<dim3(32,32), 256, 0, stream>>>(xn_bf, ipbf, nullptr, xz,
        nullptr, nullptr, nullptr, NTOK, 2*D_INNER, DIM, DIM);
    // 3. conv + silu -> xcs_bf only (for x_proj); scans recompute conv in-register
    conv_kernel<<<(NTOK*D_INNER)/256, 256, 0, stream>>>(xz, conv0, conv_w, conv_b, xcs_bf);
    // 4. proj = xcs @ x_proj^T  (K-split fast GEMM + reduce)
    cvt_pad_xproj<<<256, 256, 0, stream>>>(x_proj, xpw);
    xproj_ks_kernel<<<dim3(1,32,XPJ_KS), 256, 0, stream>>>(xcs_bf, xpw, xpart);
    xproj_reduce<<<(NTOK*96)/256, 256, 0, stream>>>(xpart, proj);
    // 5. dtp = softplus(proj[:,:64] @ dt_proj^T + dt_b)  (f32)
    dt_gemm<<<dim3(16,32), 256, 0, stream>>>(proj, dt_proj, dt_b, dtp,
        NTOK, D_INNER, DT_RANK, 96);
    // 6. chunked scan with inline conv (f32-exact)
    scan_pass1<<<1024, 256, 0, stream>>>(dtp, proj, xz, conv0, conv_w, conv_b, A_log, hend, sdt);
    scan_combine<<<256, 256, 0, stream>>>(hend, sdt, A_log, ssm0, hst);
    scan_pass3<<<1024, 256, 0, stream>>>(dtp, proj, xz, conv0, conv_w, conv_b, A_log, Dp, hst, ym_bf);
    // 6b. out_proj -> bf16 (R2; sdt dead after combine)
    cvt_w_kernel<<<512, 256, 0, stream>>>(out_proj, opbf, (DIM*D_INNER)/4);
    // 7. x1 = x + ym @ out_proj^T
    mfma_gemm_fast<0,1,0,1><<<dim3(8,32), 256, 0, stream>>>(ym_bf, opbf, x, x1,
        nullptr, nullptr, nullptr, NTOK, DIM, D_INNER, D_INNER);
    // 8. LN2 + router fused -> xn2bf, tw, ti, counts
    ln2_router_kernel<<<NTOK, 256, 0, stream>>>(x1, ln2_s, ln2_b, router_w,
        xn2bf, tw, ti, counts);
    // 9. slot assignment + ALL MoE weight cvts in one dispatch
    offs_kernel<<<1, 64, 0, stream>>>(counts, offs);
    assign_kernel<<<NTOK/256, 256, 0, stream>>>(ti, offs, cursors, tok_of_slot, slot_of);
    cvt_w3_kernel<<<2048, 256, 0, stream>>>(w_gate, wgbf, w_up, wubf, w_down, wdbf,
        (N_EXP*HID*DIM)/4);
    // 10. MoE: fused gate+up, then down (bf16 out, dnout in R1)
    moe_gateup_fast<<<dim3(HID/128, 32, N_EXP), 256, 0, stream>>>(xn2bf, wgbf, wubf,
        tok_of_slot, counts, offs, H);
    mfma_gemm_fast<2,0,1,0><<<dim3(DIM/128, 64, N_EXP), 256, 0, stream>>>(H, wdbf, nullptr, dnout,
        tok_of_slot, counts, offs, NSLOT, DIM, HID, HID);
    // 11. out = x1 + weighted experts
    final_kernel<<<(NTOK*DIM/4)/256, 256, 0, stream>>>(x1, dnout, tw, slot_of, out);
}